// Round 4
// baseline (333.170 us; speedup 1.0000x reference)
//
#include <hip/hip_runtime.h>
#include <hip/hip_bf16.h>
#include <math.h>

#define NV     32768
#define HIDDEN 768
#define SCALE  0.17677669529663687f

typedef __attribute__((ext_vector_type(8))) short short8;
typedef __attribute__((ext_vector_type(4))) float floatx4;

__device__ __forceinline__ void gload16(const void* g, void* l) {
    __builtin_amdgcn_global_load_lds(
        (const __attribute__((address_space(1))) unsigned int*)g,
        (__attribute__((address_space(3))) unsigned int*)l, 16, 0, 0);
}

__device__ __forceinline__ float bf2f(short s) {
    unsigned u = ((unsigned)(unsigned short)s) << 16;
    return __builtin_bit_cast(float, u);
}
__device__ __forceinline__ short f2bfs(float f) {
    __hip_bfloat16 b = __float2bfloat16(f);
    return *reinterpret_cast<short*>(&b);
}

// ---------------------------------------------------------------------------
// Transpose in: x[C,H,W,D] -> h[v=(z*32+y)*32+x][C]  (fp32)
__global__ __launch_bounds__(256) void tin_kernel(const float* __restrict__ xin,
                                                  float* __restrict__ h) {
    __shared__ float lds[32 * 193];
    int yx = blockIdx.x;
    int y = yx >> 5, x = yx & 31;
    for (int idx = threadIdx.x; idx < 192 * 32; idx += 256) {
        int c = idx >> 5, z = idx & 31;
        lds[z * 193 + c] = xin[(((size_t)c * 32 + y) * 32 + x) * 32 + z];
    }
    __syncthreads();
    for (int idx = threadIdx.x; idx < 32 * 192; idx += 256) {
        int z = idx / 192, c = idx - z * 192;
        h[((size_t)((z * 32 + y) * 32 + x)) * 192 + c] = lds[z * 193 + c];
    }
}

// Transpose out: h[v][C] -> out[C,H,W,D]
__global__ __launch_bounds__(256) void tout_kernel(const float* __restrict__ h,
                                                   float* __restrict__ outp) {
    __shared__ float lds[32 * 193];
    int yx = blockIdx.x;
    int y = yx >> 5, x = yx & 31;
    for (int idx = threadIdx.x; idx < 32 * 192; idx += 256) {
        int z = idx / 192, c = idx - z * 192;
        lds[z * 193 + c] = h[((size_t)((z * 32 + y) * 32 + x)) * 192 + c];
    }
    __syncthreads();
    for (int idx = threadIdx.x; idx < 192 * 32; idx += 256) {
        int c = idx >> 5, z = idx & 31;
        outp[(((size_t)c * 32 + y) * 32 + x) * 32 + z] = lds[z * 193 + c];
    }
}

// Weight prep: f32 w[R][Cc] -> bf16, optionally transposed to [Cc][R]
__global__ __launch_bounds__(256) void wprep_kernel(const float* __restrict__ w,
                                                    __hip_bfloat16* __restrict__ o,
                                                    int R, int Cc, int tr) {
    int i = blockIdx.x * 256 + threadIdx.x;
    if (i >= R * Cc) return;
    int r = i / Cc, c = i - r * Cc;
    o[tr ? (size_t)c * R + r : (size_t)i] = (__hip_bfloat16)w[i];
}

// LayerNorm over C=192 per voxel, fp32 in -> bf16 out. One wave per voxel.
__global__ __launch_bounds__(256) void ln_kernel(const float* __restrict__ in,
                                                 const float* __restrict__ g,
                                                 const float* __restrict__ be,
                                                 __hip_bfloat16* __restrict__ out) {
    int wave = threadIdx.x >> 6;
    int lane = threadIdx.x & 63;
    int v = blockIdx.x * 4 + wave;
    const float* row = in + (size_t)v * 192;
    float x0 = row[lane], x1 = row[lane + 64], x2 = row[lane + 128];
    float s = x0 + x1 + x2;
    #pragma unroll
    for (int m = 32; m; m >>= 1) s += __shfl_xor(s, m);
    float mu = s * (1.f / 192.f);
    float d0 = x0 - mu, d1 = x1 - mu, d2 = x2 - mu;
    float s2 = d0 * d0 + d1 * d1 + d2 * d2;
    #pragma unroll
    for (int m = 32; m; m >>= 1) s2 += __shfl_xor(s2, m);
    float rstd = rsqrtf(s2 * (1.f / 192.f) + 1e-5f);
    __hip_bfloat16* orow = out + (size_t)v * 192;
    orow[lane]       = (__hip_bfloat16)(d0 * rstd * g[lane]       + be[lane]);
    orow[lane + 64]  = (__hip_bfloat16)(d1 * rstd * g[lane + 64]  + be[lane + 64]);
    orow[lane + 128] = (__hip_bfloat16)(d2 * rstd * g[lane + 128] + be[lane + 128]);
}

// ---------------------------------------------------------------------------
// bf16 MFMA GEMM: C = epi(A[M,K] @ Bw[N,K]^T). 128x64 tile, BK=64, 4 waves.
// MODE 1: +bias +res(f32) -> f32 out. MODE 2: +bias, GELU -> bf16 out.
// MODE 3: scatter into attention layout [part][di][h][v][32] bf16.
template <int MODE>
__global__ __launch_bounds__(256, 2) void mgemm_kernel(
        const __hip_bfloat16* __restrict__ A,
        const __hip_bfloat16* __restrict__ Bw,
        void* __restrict__ Cp,
        const float* __restrict__ bias,
        const float* __restrict__ res,
        int M, int N, int K) {
    __shared__ short Asm[128 * 64];
    __shared__ short Bsm[64 * 64];
    const int tid = threadIdx.x;
    const int lane = tid & 63;
    const int wave = tid >> 6;
    const int wm = wave >> 1, wn = wave & 1;
    const int m0 = blockIdx.x * 128;
    const int n0 = blockIdx.y * 64;

    const int srow = lane >> 3;
    const int scol = ((lane & 7) ^ ((lane >> 3) & 7)) * 16;

    floatx4 acc[4][2] = {};

    for (int k0 = 0; k0 < K; k0 += 64) {
        #pragma unroll
        for (int s = 0; s < 4; ++s) {
            int seg = wave * 4 + s;
            const char* g = (const char*)(A + (size_t)(m0 + seg * 8 + srow) * K + k0) + scol;
            gload16(g, (char*)Asm + seg * 1024);
        }
        #pragma unroll
        for (int s = 0; s < 2; ++s) {
            int seg = wave * 2 + s;
            const char* g = (const char*)(Bw + (size_t)(n0 + seg * 8 + srow) * K + k0) + scol;
            gload16(g, (char*)Bsm + seg * 1024);
        }
        __syncthreads();
        #pragma unroll
        for (int ks = 0; ks < 2; ++ks) {
            short8 af[4], bfr[2];
            const int cb = ks * 64 + (lane >> 4) * 16;
            #pragma unroll
            for (int i = 0; i < 4; ++i) {
                int row = wm * 64 + i * 16 + (lane & 15);
                af[i] = *reinterpret_cast<const short8*>(
                    (const char*)Asm + row * 128 + (cb ^ ((row & 7) << 4)));
            }
            #pragma unroll
            for (int j = 0; j < 2; ++j) {
                int row = wn * 32 + j * 16 + (lane & 15);
                bfr[j] = *reinterpret_cast<const short8*>(
                    (const char*)Bsm + row * 128 + (cb ^ ((row & 7) << 4)));
            }
            #pragma unroll
            for (int i = 0; i < 4; ++i)
                #pragma unroll
                for (int j = 0; j < 2; ++j)
                    acc[i][j] = __builtin_amdgcn_mfma_f32_16x16x32_bf16(
                        af[i], bfr[j], acc[i][j], 0, 0, 0);
        }
        __syncthreads();
    }

    const int r4 = (lane >> 4) * 4;
    const int cc = lane & 15;
    #pragma unroll
    for (int i = 0; i < 4; ++i) {
        #pragma unroll
        for (int j = 0; j < 2; ++j) {
            int colg = n0 + wn * 32 + j * 16 + cc;
            float bv = (MODE == 1 || MODE == 2) ? bias[colg] : 0.f;
            #pragma unroll
            for (int rg = 0; rg < 4; ++rg) {
                int rowg = m0 + wm * 64 + i * 16 + r4 + rg;
                float v = acc[i][j][rg];
                if (MODE == 1 || MODE == 2) v += bv;
                if (MODE == 2) v = 0.5f * v * (1.f + erff(v * 0.70710678118654752f));
                if (MODE == 1) {
                    v += res[(size_t)rowg * N + colg];
                    ((float*)Cp)[(size_t)rowg * N + colg] = v;
                } else if (MODE == 2) {
                    ((__hip_bfloat16*)Cp)[(size_t)rowg * N + colg] = (__hip_bfloat16)v;
                } else {  // MODE 3: part/di/h scatter
                    int part = colg / 192;
                    int rem  = colg - part * 192;
                    int di   = rem >> 6, hc = rem & 63;
                    size_t addr = (size_t)part * (6 * (size_t)NV * 32)
                                + (size_t)((di << 1) + (hc >> 5)) * ((size_t)NV * 32)
                                + (size_t)rowg * 32 + (hc & 31);
                    ((__hip_bfloat16*)Cp)[addr] = (__hip_bfloat16)v;
                }
            }
        }
    }
}

// ---------------------------------------------------------------------------
// Attention: half-voxel per lane. lane = x*2 + half; each lane owns 16 ch.
// Wave covers one x-row (32 voxels); block = 4 rows; grid = (256, 6).
// Layouts qa/ka/va: [(di*2+h)][v][32ch] bf16.
__global__ __launch_bounds__(256, 4) void attn_kernel(
        const __hip_bfloat16* __restrict__ qa,
        const __hip_bfloat16* __restrict__ ka,
        const __hip_bfloat16* __restrict__ va,
        __hip_bfloat16* __restrict__ attn_out) {
    const int dh = blockIdx.y;          // di*2+h
    const int di = dh >> 1;
    const int r  = di + 1;
    const int wave = threadIdx.x >> 6, lane = threadIdx.x & 63;
    const int yz = blockIdx.x * 4 + wave;       // 0..1023
    const int z = yz >> 5, y = yz & 31;
    const int x = lane >> 1;
    const int v = (z << 10) + (y << 5) + x;
    const int co = (lane & 1) << 4;             // channel offset within head

    const __hip_bfloat16* qb = qa + (size_t)dh * NV * 32 + co;
    const __hip_bfloat16* kb = ka + (size_t)dh * NV * 32 + co;
    const __hip_bfloat16* vb = va + (size_t)dh * NV * 32 + co;

    float qf[16];
    {
        const short8* qp = reinterpret_cast<const short8*>(qb + (size_t)v * 32);
        #pragma unroll
        for (int j = 0; j < 2; ++j) {
            short8 qv = qp[j];
            #pragma unroll
            for (int u = 0; u < 8; ++u) qf[j * 8 + u] = bf2f(qv[u]);
        }
    }

    float s[27];
    #pragma unroll
    for (int kk = 0; kk < 27; ++kk) {
        const int dz = kk / 9 - 1, dy = (kk / 3) % 3 - 1, dx = kk % 3 - 1;
        int nz = z + dz * r, ny = y + dy * r, nx = x + dx * r;
        bool ok = ((unsigned)nz < 32u) & ((unsigned)ny < 32u) & ((unsigned)nx < 32u);
        int nv = ok ? v + r * ((dz << 10) + (dy << 5) + dx) : v;
        const short8* kp = reinterpret_cast<const short8*>(kb + (size_t)nv * 32);
        float d = 0.f;
        #pragma unroll
        for (int j = 0; j < 2; ++j) {
            short8 kv = kp[j];
            #pragma unroll
            for (int u = 0; u < 8; ++u) d += qf[j * 8 + u] * bf2f(kv[u]);
        }
        d += __shfl_xor(d, 1);                  // combine the two half-voxels
        s[kk] = ok ? d * SCALE : 0.f;
    }

    float mx = s[0];
    #pragma unroll
    for (int kk = 1; kk < 27; ++kk) mx = fmaxf(mx, s[kk]);

    float o[16];
    #pragma unroll
    for (int c = 0; c < 16; ++c) o[c] = 0.f;
    float denom = 0.f;
    #pragma unroll
    for (int kk = 0; kk < 27; ++kk) {
        const int dz = kk / 9 - 1, dy = (kk / 3) % 3 - 1, dx = kk % 3 - 1;
        int nz = z + dz * r, ny = y + dy * r, nx = x + dx * r;
        bool ok = ((unsigned)nz < 32u) & ((unsigned)ny < 32u) & ((unsigned)nx < 32u);
        int nv = ok ? v + r * ((dz << 10) + (dy << 5) + dx) : v;
        float p = __expf(s[kk] - mx);
        denom += p;
        float w = ok ? p : 0.f;
        const short8* vp = reinterpret_cast<const short8*>(vb + (size_t)nv * 32);
        #pragma unroll
        for (int j = 0; j < 2; ++j) {
            short8 vv = vp[j];
            #pragma unroll
            for (int u = 0; u < 8; ++u) o[j * 8 + u] += w * bf2f(vv[u]);
        }
    }
    float inv = 1.f / denom;

    __hip_bfloat16* op = attn_out + (size_t)v * 192 + di * 64 + (dh & 1) * 32 + co;
    #pragma unroll
    for (int j = 0; j < 2; ++j) {
        short8 st;
        #pragma unroll
        for (int u = 0; u < 8; ++u) st[u] = f2bfs(o[j * 8 + u] * inv);
        *reinterpret_cast<short8*>(op + j * 8) = st;
    }
}

// ---------------------------------------------------------------------------
extern "C" void kernel_launch(void* const* d_in, const int* in_sizes, int n_in,
                              void* d_out, int out_size, void* d_ws, size_t ws_size,
                              hipStream_t stream) {
    const float* x      = (const float*)d_in[0];
    const float* qkv_w  = (const float*)d_in[1];
    const float* proj_w = (const float*)d_in[2];
    const float* proj_b = (const float*)d_in[3];
    const float* g1     = (const float*)d_in[4];
    const float* be1    = (const float*)d_in[5];
    const float* g2     = (const float*)d_in[6];
    const float* be2    = (const float*)d_in[7];
    const float* w1     = (const float*)d_in[8];
    const float* b1     = (const float*)d_in[9];
    const float* w2     = (const float*)d_in[10];
    const float* b2     = (const float*)d_in[11];
    float* out = (float*)d_out;

    char* p = (char*)d_ws;
    float* h = (float*)p;                        p += (size_t)NV * 192 * 4;
    __hip_bfloat16* lnb   = (__hip_bfloat16*)p;  p += (size_t)NV * 192 * 2;
    __hip_bfloat16* qkvb  = (__hip_bfloat16*)p;  p += (size_t)NV * 576 * 2;
    __hip_bfloat16* attnb = (__hip_bfloat16*)p;  p += (size_t)NV * 192 * 2;
    __hip_bfloat16* tb    = qkvb;  // [NV][768] overlaps dead qkvb+attnb exactly
    __hip_bfloat16* wqkv  = (__hip_bfloat16*)p;  p += (size_t)576 * 192 * 2;
    __hip_bfloat16* wproj = (__hip_bfloat16*)p;  p += (size_t)192 * 192 * 2;
    __hip_bfloat16* w1t   = (__hip_bfloat16*)p;  p += (size_t)768 * 192 * 2;
    __hip_bfloat16* w2t   = (__hip_bfloat16*)p;  p += (size_t)192 * 768 * 2;

    __hip_bfloat16* qa = qkvb;
    __hip_bfloat16* ka = qkvb + (size_t)6 * NV * 32;
    __hip_bfloat16* va = qkvb + (size_t)12 * NV * 32;

    // layout + weight prep
    tin_kernel<<<1024, 256, 0, stream>>>(x, h);
    wprep_kernel<<<(576 * 192 + 255) / 256, 256, 0, stream>>>(qkv_w, wqkv, 576, 192, 0);
    wprep_kernel<<<(192 * 192 + 255) / 256, 256, 0, stream>>>(proj_w, wproj, 192, 192, 1);
    wprep_kernel<<<(192 * 768 + 255) / 256, 256, 0, stream>>>(w1, w1t, 192, 768, 1);
    wprep_kernel<<<(768 * 192 + 255) / 256, 256, 0, stream>>>(w2, w2t, 768, 192, 1);

    // LN1 -> QKV (scatter to attn layout) -> attn -> proj(+res)
    ln_kernel<<<NV / 4, 256, 0, stream>>>(h, g1, be1, lnb);
    mgemm_kernel<3><<<dim3(NV / 128, 576 / 64), 256, 0, stream>>>(
        lnb, wqkv, qkvb, nullptr, nullptr, NV, 576, 192);
    attn_kernel<<<dim3(256, 6), 256, 0, stream>>>(qa, ka, va, attnb);
    mgemm_kernel<1><<<dim3(NV / 128, 192 / 64), 256, 0, stream>>>(
        attnb, wproj, h, proj_b, h, NV, 192, 192);

    // LN2 -> MLP
    ln_kernel<<<NV / 4, 256, 0, stream>>>(h, g2, be2, lnb);
    mgemm_kernel<2><<<dim3(NV / 128, HIDDEN / 64), 256, 0, stream>>>(
        lnb, w1t, tb, b1, nullptr, NV, HIDDEN, 192);
    mgemm_kernel<1><<<dim3(NV / 128, 192 / 64), 256, 0, stream>>>(
        tb, w2t, h, b2, h, NV, 192, HIDDEN);

    tout_kernel<<<1024, 256, 0, stream>>>(h, out);
}

// Round 5
// 177.442 us; speedup vs baseline: 1.8776x; 1.8776x over previous
//
#include <hip/hip_runtime.h>
#include <hip/hip_bf16.h>
#include <math.h>

#define NV     32768
#define HIDDEN 768
#define SCALE  0.17677669529663687f

typedef __attribute__((ext_vector_type(8))) short short8;
typedef __attribute__((ext_vector_type(4))) float floatx4;

__device__ __forceinline__ void gload16(const void* g, void* l) {
    __builtin_amdgcn_global_load_lds(
        (const __attribute__((address_space(1))) unsigned int*)g,
        (__attribute__((address_space(3))) unsigned int*)l, 16, 0, 0);
}

__device__ __forceinline__ float bf2f(short s) {
    unsigned u = ((unsigned)(unsigned short)s) << 16;
    return __builtin_bit_cast(float, u);
}
__device__ __forceinline__ short f2bfs(float f) {
    __hip_bfloat16 b = __float2bfloat16(f);
    return *reinterpret_cast<short*>(&b);
}

// ---------------------------------------------------------------------------
// Transpose in: x[C,H,W,D] -> h[v=(z*32+y)*32+x][C]  (fp32)
__global__ __launch_bounds__(256) void tin_kernel(const float* __restrict__ xin,
                                                  float* __restrict__ h) {
    __shared__ float lds[32 * 193];
    int yx = blockIdx.x;
    int y = yx >> 5, x = yx & 31;
    for (int idx = threadIdx.x; idx < 192 * 32; idx += 256) {
        int c = idx >> 5, z = idx & 31;
        lds[z * 193 + c] = xin[(((size_t)c * 32 + y) * 32 + x) * 32 + z];
    }
    __syncthreads();
    for (int idx = threadIdx.x; idx < 32 * 192; idx += 256) {
        int z = idx / 192, c = idx - z * 192;
        h[((size_t)((z * 32 + y) * 32 + x)) * 192 + c] = lds[z * 193 + c];
    }
}

// Transpose out: h[v][C] -> out[C,H,W,D]
__global__ __launch_bounds__(256) void tout_kernel(const float* __restrict__ h,
                                                   float* __restrict__ outp) {
    __shared__ float lds[32 * 193];
    int yx = blockIdx.x;
    int y = yx >> 5, x = yx & 31;
    for (int idx = threadIdx.x; idx < 32 * 192; idx += 256) {
        int z = idx / 192, c = idx - z * 192;
        lds[z * 193 + c] = h[((size_t)((z * 32 + y) * 32 + x)) * 192 + c];
    }
    __syncthreads();
    for (int idx = threadIdx.x; idx < 192 * 32; idx += 256) {
        int c = idx >> 5, z = idx & 31;
        outp[(((size_t)c * 32 + y) * 32 + x) * 32 + z] = lds[z * 193 + c];
    }
}

// Weight prep: f32 w[R][Cc] -> bf16, optionally transposed to [Cc][R]
__global__ __launch_bounds__(256) void wprep_kernel(const float* __restrict__ w,
                                                    __hip_bfloat16* __restrict__ o,
                                                    int R, int Cc, int tr) {
    int i = blockIdx.x * 256 + threadIdx.x;
    if (i >= R * Cc) return;
    int r = i / Cc, c = i - r * Cc;
    o[tr ? (size_t)c * R + r : (size_t)i] = (__hip_bfloat16)w[i];
}

// LayerNorm over C=192 per voxel, fp32 in -> bf16 out. One wave per voxel.
__global__ __launch_bounds__(256) void ln_kernel(const float* __restrict__ in,
                                                 const float* __restrict__ g,
                                                 const float* __restrict__ be,
                                                 __hip_bfloat16* __restrict__ out) {
    int wave = threadIdx.x >> 6;
    int lane = threadIdx.x & 63;
    int v = blockIdx.x * 4 + wave;
    const float* row = in + (size_t)v * 192;
    float x0 = row[lane], x1 = row[lane + 64], x2 = row[lane + 128];
    float s = x0 + x1 + x2;
    #pragma unroll
    for (int m = 32; m; m >>= 1) s += __shfl_xor(s, m);
    float mu = s * (1.f / 192.f);
    float d0 = x0 - mu, d1 = x1 - mu, d2 = x2 - mu;
    float s2 = d0 * d0 + d1 * d1 + d2 * d2;
    #pragma unroll
    for (int m = 32; m; m >>= 1) s2 += __shfl_xor(s2, m);
    float rstd = rsqrtf(s2 * (1.f / 192.f) + 1e-5f);
    __hip_bfloat16* orow = out + (size_t)v * 192;
    orow[lane]       = (__hip_bfloat16)(d0 * rstd * g[lane]       + be[lane]);
    orow[lane + 64]  = (__hip_bfloat16)(d1 * rstd * g[lane + 64]  + be[lane + 64]);
    orow[lane + 128] = (__hip_bfloat16)(d2 * rstd * g[lane + 128] + be[lane + 128]);
}

// ---------------------------------------------------------------------------
// bf16 MFMA GEMM: C = epi(A[M,K] @ Bw[N,K]^T). 128x64 tile, BK=64, 4 waves.
// MODE 1: +bias +res(f32) -> f32 out. MODE 2: +bias, GELU -> bf16 out.
// MODE 3: scatter into attention layout [part][di][h][v][32] bf16.
template <int MODE>
__global__ __launch_bounds__(256, 2) void mgemm_kernel(
        const __hip_bfloat16* __restrict__ A,
        const __hip_bfloat16* __restrict__ Bw,
        void* __restrict__ Cp,
        const float* __restrict__ bias,
        const float* __restrict__ res,
        int M, int N, int K) {
    __shared__ short Asm[128 * 64];
    __shared__ short Bsm[64 * 64];
    const int tid = threadIdx.x;
    const int lane = tid & 63;
    const int wave = tid >> 6;
    const int wm = wave >> 1, wn = wave & 1;
    const int m0 = blockIdx.x * 128;
    const int n0 = blockIdx.y * 64;

    const int srow = lane >> 3;
    const int scol = ((lane & 7) ^ ((lane >> 3) & 7)) * 16;

    floatx4 acc[4][2] = {};

    for (int k0 = 0; k0 < K; k0 += 64) {
        #pragma unroll
        for (int s = 0; s < 4; ++s) {
            int seg = wave * 4 + s;
            const char* g = (const char*)(A + (size_t)(m0 + seg * 8 + srow) * K + k0) + scol;
            gload16(g, (char*)Asm + seg * 1024);
        }
        #pragma unroll
        for (int s = 0; s < 2; ++s) {
            int seg = wave * 2 + s;
            const char* g = (const char*)(Bw + (size_t)(n0 + seg * 8 + srow) * K + k0) + scol;
            gload16(g, (char*)Bsm + seg * 1024);
        }
        __syncthreads();
        #pragma unroll
        for (int ks = 0; ks < 2; ++ks) {
            short8 af[4], bfr[2];
            const int cb = ks * 64 + (lane >> 4) * 16;
            #pragma unroll
            for (int i = 0; i < 4; ++i) {
                int row = wm * 64 + i * 16 + (lane & 15);
                af[i] = *reinterpret_cast<const short8*>(
                    (const char*)Asm + row * 128 + (cb ^ ((row & 7) << 4)));
            }
            #pragma unroll
            for (int j = 0; j < 2; ++j) {
                int row = wn * 32 + j * 16 + (lane & 15);
                bfr[j] = *reinterpret_cast<const short8*>(
                    (const char*)Bsm + row * 128 + (cb ^ ((row & 7) << 4)));
            }
            #pragma unroll
            for (int i = 0; i < 4; ++i)
                #pragma unroll
                for (int j = 0; j < 2; ++j)
                    acc[i][j] = __builtin_amdgcn_mfma_f32_16x16x32_bf16(
                        af[i], bfr[j], acc[i][j], 0, 0, 0);
        }
        __syncthreads();
    }

    const int r4 = (lane >> 4) * 4;
    const int cc = lane & 15;
    #pragma unroll
    for (int i = 0; i < 4; ++i) {
        #pragma unroll
        for (int j = 0; j < 2; ++j) {
            int colg = n0 + wn * 32 + j * 16 + cc;
            float bv = (MODE == 1 || MODE == 2) ? bias[colg] : 0.f;
            #pragma unroll
            for (int rg = 0; rg < 4; ++rg) {
                int rowg = m0 + wm * 64 + i * 16 + r4 + rg;
                float v = acc[i][j][rg];
                if (MODE == 1 || MODE == 2) v += bv;
                if (MODE == 2) v = 0.5f * v * (1.f + erff(v * 0.70710678118654752f));
                if (MODE == 1) {
                    v += res[(size_t)rowg * N + colg];
                    ((float*)Cp)[(size_t)rowg * N + colg] = v;
                } else if (MODE == 2) {
                    ((__hip_bfloat16*)Cp)[(size_t)rowg * N + colg] = (__hip_bfloat16)v;
                } else {  // MODE 3: part/di/h scatter
                    int part = colg / 192;
                    int rem  = colg - part * 192;
                    int di   = rem >> 6, hc = rem & 63;
                    size_t addr = (size_t)part * (6 * (size_t)NV * 32)
                                + (size_t)((di << 1) + (hc >> 5)) * ((size_t)NV * 32)
                                + (size_t)rowg * 32 + (hc & 31);
                    ((__hip_bfloat16*)Cp)[addr] = (__hip_bfloat16)v;
                }
            }
        }
    }
}

// ---------------------------------------------------------------------------
// Attention: half-voxel per lane. lane = x*2 + half; each lane owns 16 ch.
// Wave covers one x-row (32 voxels); block = 4 rows; grid = (256, 6).
// Layouts qa/ka/va: [(di*2+h)][v][32ch] bf16.
// NOTE: no occupancy floor — round 4's (256,4) forced VGPR=64 and spilled
// ~100 live regs to scratch (396 MB phantom writes). Let allocator pick.
__global__ __launch_bounds__(256) void attn_kernel(
        const __hip_bfloat16* __restrict__ qa,
        const __hip_bfloat16* __restrict__ ka,
        const __hip_bfloat16* __restrict__ va,
        __hip_bfloat16* __restrict__ attn_out) {
    const int dh = blockIdx.y;          // di*2+h
    const int di = dh >> 1;
    const int r  = di + 1;
    const int wave = threadIdx.x >> 6, lane = threadIdx.x & 63;
    const int yz = blockIdx.x * 4 + wave;       // 0..1023
    const int z = yz >> 5, y = yz & 31;
    const int x = lane >> 1;
    const int v = (z << 10) + (y << 5) + x;
    const int co = (lane & 1) << 4;             // channel offset within head

    const __hip_bfloat16* qb = qa + (size_t)dh * NV * 32 + co;
    const __hip_bfloat16* kb = ka + (size_t)dh * NV * 32 + co;
    const __hip_bfloat16* vb = va + (size_t)dh * NV * 32 + co;

    float qf[16];
    {
        const short8* qp = reinterpret_cast<const short8*>(qb + (size_t)v * 32);
        #pragma unroll
        for (int j = 0; j < 2; ++j) {
            short8 qv = qp[j];
            #pragma unroll
            for (int u = 0; u < 8; ++u) qf[j * 8 + u] = bf2f(qv[u]);
        }
    }

    float s[27];
    #pragma unroll
    for (int kk = 0; kk < 27; ++kk) {
        const int dz = kk / 9 - 1, dy = (kk / 3) % 3 - 1, dx = kk % 3 - 1;
        int nz = z + dz * r, ny = y + dy * r, nx = x + dx * r;
        bool ok = ((unsigned)nz < 32u) & ((unsigned)ny < 32u) & ((unsigned)nx < 32u);
        int nv = ok ? v + r * ((dz << 10) + (dy << 5) + dx) : v;
        const short8* kp = reinterpret_cast<const short8*>(kb + (size_t)nv * 32);
        float d = 0.f;
        #pragma unroll
        for (int j = 0; j < 2; ++j) {
            short8 kv = kp[j];
            #pragma unroll
            for (int u = 0; u < 8; ++u) d += qf[j * 8 + u] * bf2f(kv[u]);
        }
        d += __shfl_xor(d, 1);                  // combine the two half-voxels
        s[kk] = ok ? d * SCALE : 0.f;
    }

    float mx = s[0];
    #pragma unroll
    for (int kk = 1; kk < 27; ++kk) mx = fmaxf(mx, s[kk]);

    float o[16];
    #pragma unroll
    for (int c = 0; c < 16; ++c) o[c] = 0.f;
    float denom = 0.f;
    #pragma unroll
    for (int kk = 0; kk < 27; ++kk) {
        const int dz = kk / 9 - 1, dy = (kk / 3) % 3 - 1, dx = kk % 3 - 1;
        int nz = z + dz * r, ny = y + dy * r, nx = x + dx * r;
        bool ok = ((unsigned)nz < 32u) & ((unsigned)ny < 32u) & ((unsigned)nx < 32u);
        int nv = ok ? v + r * ((dz << 10) + (dy << 5) + dx) : v;
        float p = __expf(s[kk] - mx);
        denom += p;
        float w = ok ? p : 0.f;
        const short8* vp = reinterpret_cast<const short8*>(vb + (size_t)nv * 32);
        #pragma unroll
        for (int j = 0; j < 2; ++j) {
            short8 vv = vp[j];
            #pragma unroll
            for (int u = 0; u < 8; ++u) o[j * 8 + u] += w * bf2f(vv[u]);
        }
    }
    float inv = 1.f / denom;

    __hip_bfloat16* op = attn_out + (size_t)v * 192 + di * 64 + (dh & 1) * 32 + co;
    #pragma unroll
    for (int j = 0; j < 2; ++j) {
        short8 st;
        #pragma unroll
        for (int u = 0; u < 8; ++u) st[u] = f2bfs(o[j * 8 + u] * inv);
        *reinterpret_cast<short8*>(op + j * 8) = st;
    }
}

// ---------------------------------------------------------------------------
extern "C" void kernel_launch(void* const* d_in, const int* in_sizes, int n_in,
                              void* d_out, int out_size, void* d_ws, size_t ws_size,
                              hipStream_t stream) {
    const float* x      = (const float*)d_in[0];
    const float* qkv_w  = (const float*)d_in[1];
    const float* proj_w = (const float*)d_in[2];
    const float* proj_b = (const float*)d_in[3];
    const float* g1     = (const float*)d_in[4];
    const float* be1    = (const float*)d_in[5];
    const float* g2     = (const float*)d_in[6];
    const float* be2    = (const float*)d_in[7];
    const float* w1     = (const float*)d_in[8];
    const float* b1     = (const float*)d_in[9];
    const float* w2     = (const float*)d_in[10];
    const float* b2     = (const float*)d_in[11];
    float* out = (float*)d_out;

    char* p = (char*)d_ws;
    float* h = (float*)p;                        p += (size_t)NV * 192 * 4;
    __hip_bfloat16* lnb   = (__hip_bfloat16*)p;  p += (size_t)NV * 192 * 2;
    __hip_bfloat16* qkvb  = (__hip_bfloat16*)p;  p += (size_t)NV * 576 * 2;
    __hip_bfloat16* attnb = (__hip_bfloat16*)p;  p += (size_t)NV * 192 * 2;
    __hip_bfloat16* tb    = qkvb;  // [NV][768] overlaps dead qkvb+attnb exactly
    __hip_bfloat16* wqkv  = (__hip_bfloat16*)p;  p += (size_t)576 * 192 * 2;
    __hip_bfloat16* wproj = (__hip_bfloat16*)p;  p += (size_t)192 * 192 * 2;
    __hip_bfloat16* w1t   = (__hip_bfloat16*)p;  p += (size_t)768 * 192 * 2;
    __hip_bfloat16* w2t   = (__hip_bfloat16*)p;  p += (size_t)192 * 768 * 2;

    __hip_bfloat16* qa = qkvb;
    __hip_bfloat16* ka = qkvb + (size_t)6 * NV * 32;
    __hip_bfloat16* va = qkvb + (size_t)12 * NV * 32;

    // layout + weight prep
    tin_kernel<<<1024, 256, 0, stream>>>(x, h);
    wprep_kernel<<<(576 * 192 + 255) / 256, 256, 0, stream>>>(qkv_w, wqkv, 576, 192, 0);
    wprep_kernel<<<(192 * 192 + 255) / 256, 256, 0, stream>>>(proj_w, wproj, 192, 192, 1);
    wprep_kernel<<<(192 * 768 + 255) / 256, 256, 0, stream>>>(w1, w1t, 192, 768, 1);
    wprep_kernel<<<(768 * 192 + 255) / 256, 256, 0, stream>>>(w2, w2t, 768, 192, 1);

    // LN1 -> QKV (scatter to attn layout) -> attn -> proj(+res)
    ln_kernel<<<NV / 4, 256, 0, stream>>>(h, g1, be1, lnb);
    mgemm_kernel<3><<<dim3(NV / 128, 576 / 64), 256, 0, stream>>>(
        lnb, wqkv, qkvb, nullptr, nullptr, NV, 576, 192);
    attn_kernel<<<dim3(256, 6), 256, 0, stream>>>(qa, ka, va, attnb);
    mgemm_kernel<1><<<dim3(NV / 128, 192 / 64), 256, 0, stream>>>(
        attnb, wproj, h, proj_b, h, NV, 192, 192);

    // LN2 -> MLP
    ln_kernel<<<NV / 4, 256, 0, stream>>>(h, g2, be2, lnb);
    mgemm_kernel<2><<<dim3(NV / 128, HIDDEN / 64), 256, 0, stream>>>(
        lnb, w1t, tb, b1, nullptr, NV, HIDDEN, 192);
    mgemm_kernel<1><<<dim3(NV / 128, 192 / 64), 256, 0, stream>>>(
        tb, w2t, h, b2, h, NV, 192, HIDDEN);

    tout_kernel<<<1024, 256, 0, stream>>>(h, out);
}

// Round 6
// 161.344 us; speedup vs baseline: 2.0650x; 1.0998x over previous
//
#include <hip/hip_runtime.h>
#include <hip/hip_bf16.h>
#include <math.h>

#define NV     32768
#define HIDDEN 768
#define SCALE  0.17677669529663687f

typedef __attribute__((ext_vector_type(8))) short short8;
typedef __attribute__((ext_vector_type(4))) float floatx4;
typedef __hip_bfloat16 bf16;

__device__ __forceinline__ void gload16(const void* g, void* l) {
    __builtin_amdgcn_global_load_lds(
        (const __attribute__((address_space(1))) unsigned int*)g,
        (__attribute__((address_space(3))) unsigned int*)l, 16, 0, 0);
}

__device__ __forceinline__ float bf2f(short s) {
    unsigned u = ((unsigned)(unsigned short)s) << 16;
    return __builtin_bit_cast(float, u);
}
__device__ __forceinline__ short f2bfs(float f) {
    bf16 b = __float2bfloat16(f);
    return *reinterpret_cast<short*>(&b);
}

// ---------------------------------------------------------------------------
// All weight converts in one kernel.
// qkv_w[576][192] -> wqkv (no tr); proj_w[192][192] -> wproj^T;
// w1[192][768] -> w1t[768][192]; w2[768][192] -> w2t[192][768].
__global__ __launch_bounds__(256) void prep_kernel(
        const float* __restrict__ qkv_w, const float* __restrict__ proj_w,
        const float* __restrict__ w1, const float* __restrict__ w2,
        bf16* __restrict__ wqkv, bf16* __restrict__ wproj,
        bf16* __restrict__ w1t, bf16* __restrict__ w2t) {
    int i = blockIdx.x * 256 + threadIdx.x;
    if (i < 110592) {
        wqkv[i] = (bf16)qkv_w[i];
    } else if (i < 147456) {
        int j = i - 110592; int r = j / 192, c = j - r * 192;
        wproj[c * 192 + r] = (bf16)proj_w[j];
    } else if (i < 294912) {
        int j = i - 147456; int r = j / 768, c = j - r * 768;
        w1t[c * 192 + r] = (bf16)w1[j];
    } else if (i < 442368) {
        int j = i - 294912; int r = j / 192, c = j - r * 192;
        w2t[c * 768 + r] = (bf16)w2[j];
    }
}

// ---------------------------------------------------------------------------
// Fused transpose-in + LN1: x[C,H,W,D] f32 -> h[v][192] bf16 (raw) + lnb bf16.
__global__ __launch_bounds__(256) void tin_ln_kernel(
        const float* __restrict__ xin, const float* __restrict__ g,
        const float* __restrict__ be, bf16* __restrict__ h,
        bf16* __restrict__ lnb) {
    __shared__ float lds[32 * 193];
    int yx = blockIdx.x;
    int y = yx >> 5, x = yx & 31;
    for (int idx = threadIdx.x; idx < 192 * 32; idx += 256) {
        int c = idx >> 5, z = idx & 31;
        lds[z * 193 + c] = xin[(((size_t)c * 32 + y) * 32 + x) * 32 + z];
    }
    __syncthreads();
    int wave = threadIdx.x >> 6, lane = threadIdx.x & 63;
    float ga = g[lane], gb = g[lane + 64], gc = g[lane + 128];
    float ba = be[lane], bb = be[lane + 64], bc = be[lane + 128];
    for (int z = wave; z < 32; z += 4) {
        float x0 = lds[z * 193 + lane];
        float x1 = lds[z * 193 + lane + 64];
        float x2 = lds[z * 193 + lane + 128];
        float s = x0 + x1 + x2;
        #pragma unroll
        for (int m = 32; m; m >>= 1) s += __shfl_xor(s, m);
        float mu = s * (1.f / 192.f);
        float d0 = x0 - mu, d1 = x1 - mu, d2 = x2 - mu;
        float s2 = d0 * d0 + d1 * d1 + d2 * d2;
        #pragma unroll
        for (int m = 32; m; m >>= 1) s2 += __shfl_xor(s2, m);
        float rstd = rsqrtf(s2 * (1.f / 192.f) + 1e-5f);
        size_t v = (size_t)((z << 10) + (y << 5) + x) * 192;
        h[v + lane]         = (bf16)x0;
        h[v + lane + 64]    = (bf16)x1;
        h[v + lane + 128]   = (bf16)x2;
        lnb[v + lane]       = (bf16)(d0 * rstd * ga + ba);
        lnb[v + lane + 64]  = (bf16)(d1 * rstd * gb + bb);
        lnb[v + lane + 128] = (bf16)(d2 * rstd * gc + bc);
    }
}

// Transpose out: h[v][C] bf16 -> out[C,H,W,D] f32
__global__ __launch_bounds__(256) void tout_kernel(const bf16* __restrict__ h,
                                                   float* __restrict__ outp) {
    __shared__ float lds[32 * 193];
    int yx = blockIdx.x;
    int y = yx >> 5, x = yx & 31;
    for (int idx = threadIdx.x; idx < 32 * 192; idx += 256) {
        int z = idx / 192, c = idx - z * 192;
        lds[z * 193 + c] = __bfloat162float(h[((size_t)((z * 32 + y) * 32 + x)) * 192 + c]);
    }
    __syncthreads();
    for (int idx = threadIdx.x; idx < 192 * 32; idx += 256) {
        int c = idx >> 5, z = idx & 31;
        outp[(((size_t)c * 32 + y) * 32 + x) * 32 + z] = lds[z * 193 + c];
    }
}

// ---------------------------------------------------------------------------
// bf16 MFMA GEMM: C = epi(A[M,K] @ Bw[N,K]^T). 128x64 tile, BK=64, 4 waves.
// MODE 1: +bias +res(bf16) -> bf16 (in-place capable).
// MODE 2: +bias, GELU -> bf16. MODE 3: scatter to attn layout.
template <int MODE>
__global__ __launch_bounds__(256, 2) void mgemm_kernel(
        const bf16* __restrict__ A,
        const bf16* __restrict__ Bw,
        void* __restrict__ Cp,
        const float* __restrict__ bias,
        const bf16* __restrict__ res,
        int M, int N, int K) {
    __shared__ short Asm[128 * 64];
    __shared__ short Bsm[64 * 64];
    const int tid = threadIdx.x;
    const int lane = tid & 63;
    const int wave = tid >> 6;
    const int wm = wave >> 1, wn = wave & 1;
    const int m0 = blockIdx.x * 128;
    const int n0 = blockIdx.y * 64;

    const int srow = lane >> 3;
    const int scol = ((lane & 7) ^ ((lane >> 3) & 7)) * 16;

    floatx4 acc[4][2] = {};

    for (int k0 = 0; k0 < K; k0 += 64) {
        #pragma unroll
        for (int s = 0; s < 4; ++s) {
            int seg = wave * 4 + s;
            const char* g = (const char*)(A + (size_t)(m0 + seg * 8 + srow) * K + k0) + scol;
            gload16(g, (char*)Asm + seg * 1024);
        }
        #pragma unroll
        for (int s = 0; s < 2; ++s) {
            int seg = wave * 2 + s;
            const char* g = (const char*)(Bw + (size_t)(n0 + seg * 8 + srow) * K + k0) + scol;
            gload16(g, (char*)Bsm + seg * 1024);
        }
        __syncthreads();
        #pragma unroll
        for (int ks = 0; ks < 2; ++ks) {
            short8 af[4], bfr[2];
            const int cb = ks * 64 + (lane >> 4) * 16;
            #pragma unroll
            for (int i = 0; i < 4; ++i) {
                int row = wm * 64 + i * 16 + (lane & 15);
                af[i] = *reinterpret_cast<const short8*>(
                    (const char*)Asm + row * 128 + (cb ^ ((row & 7) << 4)));
            }
            #pragma unroll
            for (int j = 0; j < 2; ++j) {
                int row = wn * 32 + j * 16 + (lane & 15);
                bfr[j] = *reinterpret_cast<const short8*>(
                    (const char*)Bsm + row * 128 + (cb ^ ((row & 7) << 4)));
            }
            #pragma unroll
            for (int i = 0; i < 4; ++i)
                #pragma unroll
                for (int j = 0; j < 2; ++j)
                    acc[i][j] = __builtin_amdgcn_mfma_f32_16x16x32_bf16(
                        af[i], bfr[j], acc[i][j], 0, 0, 0);
        }
        __syncthreads();
    }

    const int r4 = (lane >> 4) * 4;
    const int cc = lane & 15;
    #pragma unroll
    for (int i = 0; i < 4; ++i) {
        #pragma unroll
        for (int j = 0; j < 2; ++j) {
            int colg = n0 + wn * 32 + j * 16 + cc;
            float bv = (MODE == 1 || MODE == 2) ? bias[colg] : 0.f;
            #pragma unroll
            for (int rg = 0; rg < 4; ++rg) {
                int rowg = m0 + wm * 64 + i * 16 + r4 + rg;
                float v = acc[i][j][rg];
                if (MODE == 1 || MODE == 2) v += bv;
                if (MODE == 2) v = 0.5f * v * (1.f + erff(v * 0.70710678118654752f));
                if (MODE == 1) {
                    v += __bfloat162float(res[(size_t)rowg * N + colg]);
                    ((bf16*)Cp)[(size_t)rowg * N + colg] = (bf16)v;
                } else if (MODE == 2) {
                    ((bf16*)Cp)[(size_t)rowg * N + colg] = (bf16)v;
                } else {  // MODE 3: part/di/h scatter
                    int part = colg / 192;
                    int rem  = colg - part * 192;
                    int di   = rem >> 6, hc = rem & 63;
                    size_t addr = (size_t)part * (6 * (size_t)NV * 32)
                                + (size_t)((di << 1) + (hc >> 5)) * ((size_t)NV * 32)
                                + (size_t)rowg * 32 + (hc & 31);
                    ((bf16*)Cp)[addr] = (bf16)v;
                }
            }
        }
    }
}

// ---------------------------------------------------------------------------
// Fused proj GEMM + residual + LN2. Full-row tile: 64 rows x 192 cols, BK=64.
// A = attnb [M,192], Bw = wproj [192 N][192 K]. h updated in place (bf16);
// lnout = LN2(h2) bf16. 4 waves; wave owns 16 rows x 192 cols (12 col-frags).
__global__ __launch_bounds__(256) void projln_kernel(
        const bf16* __restrict__ A, const bf16* __restrict__ Bw,
        bf16* __restrict__ hres, bf16* __restrict__ lnout,
        const float* __restrict__ bias,
        const float* __restrict__ g2, const float* __restrict__ be2) {
    __shared__ short Asm[64 * 64];    // 8 KB
    __shared__ short Bsm[192 * 64];   // 24 KB
    const int tid = threadIdx.x;
    const int lane = tid & 63;
    const int wave = tid >> 6;
    const int m0 = blockIdx.x * 64;

    const int srow = lane >> 3;
    const int scol = ((lane & 7) ^ ((lane >> 3) & 7)) * 16;

    floatx4 acc[12] = {};

    for (int k0 = 0; k0 < 192; k0 += 64) {
        #pragma unroll
        for (int s = 0; s < 2; ++s) {                 // A: 8 segs
            int seg = wave * 2 + s;
            const char* g = (const char*)(A + (size_t)(m0 + seg * 8 + srow) * 192 + k0) + scol;
            gload16(g, (char*)Asm + seg * 1024);
        }
        #pragma unroll
        for (int s = 0; s < 6; ++s) {                 // B: 24 segs (192 N-rows)
            int seg = wave * 6 + s;
            const char* g = (const char*)(Bw + (size_t)(seg * 8 + srow) * 192 + k0) + scol;
            gload16(g, (char*)Bsm + seg * 1024);
        }
        __syncthreads();
        #pragma unroll
        for (int ks = 0; ks < 2; ++ks) {
            const int cb = ks * 64 + (lane >> 4) * 16;
            int arow = wave * 16 + (lane & 15);
            short8 af = *reinterpret_cast<const short8*>(
                (const char*)Asm + arow * 128 + (cb ^ ((arow & 7) << 4)));
            #pragma unroll
            for (int j = 0; j < 12; ++j) {
                int brow = j * 16 + (lane & 15);
                short8 bfr = *reinterpret_cast<const short8*>(
                    (const char*)Bsm + brow * 128 + (cb ^ ((brow & 7) << 4)));
                acc[j] = __builtin_amdgcn_mfma_f32_16x16x32_bf16(af, bfr, acc[j], 0, 0, 0);
            }
        }
        __syncthreads();
    }

    // Epilogue: +bias +res, then row LN over 192 cols (16-lane group reduce).
    const int cc = lane & 15;
    #pragma unroll
    for (int rg = 0; rg < 4; ++rg) {
        int rowg = m0 + wave * 16 + (lane >> 4) * 4 + rg;
        float vals[12];
        float vsum = 0.f;
        #pragma unroll
        for (int j = 0; j < 12; ++j) {
            int col = j * 16 + cc;
            float v = acc[j][rg] + bias[col]
                    + __bfloat162float(hres[(size_t)rowg * 192 + col]);
            vals[j] = v;
            vsum += v;
        }
        #pragma unroll
        for (int m = 8; m; m >>= 1) vsum += __shfl_xor(vsum, m);
        float mu = vsum * (1.f / 192.f);
        float vsq = 0.f;
        #pragma unroll
        for (int j = 0; j < 12; ++j) {
            float d = vals[j] - mu;
            vsq += d * d;
        }
        #pragma unroll
        for (int m = 8; m; m >>= 1) vsq += __shfl_xor(vsq, m);
        float rstd = rsqrtf(vsq * (1.f / 192.f) + 1e-5f);
        #pragma unroll
        for (int j = 0; j < 12; ++j) {
            int col = j * 16 + cc;
            hres[(size_t)rowg * 192 + col] = (bf16)vals[j];
            lnout[(size_t)rowg * 192 + col] =
                (bf16)((vals[j] - mu) * rstd * g2[col] + be2[col]);
        }
    }
}

// ---------------------------------------------------------------------------
// Attention: half-voxel per lane (unchanged from round 5).
__global__ __launch_bounds__(256) void attn_kernel(
        const bf16* __restrict__ qa,
        const bf16* __restrict__ ka,
        const bf16* __restrict__ va,
        bf16* __restrict__ attn_out) {
    const int dh = blockIdx.y;
    const int di = dh >> 1;
    const int r  = di + 1;
    const int wave = threadIdx.x >> 6, lane = threadIdx.x & 63;
    const int yz = blockIdx.x * 4 + wave;
    const int z = yz >> 5, y = yz & 31;
    const int x = lane >> 1;
    const int v = (z << 10) + (y << 5) + x;
    const int co = (lane & 1) << 4;

    const bf16* qb = qa + (size_t)dh * NV * 32 + co;
    const bf16* kb = ka + (size_t)dh * NV * 32 + co;
    const bf16* vb = va + (size_t)dh * NV * 32 + co;

    float qf[16];
    {
        const short8* qp = reinterpret_cast<const short8*>(qb + (size_t)v * 32);
        #pragma unroll
        for (int j = 0; j < 2; ++j) {
            short8 qv = qp[j];
            #pragma unroll
            for (int u = 0; u < 8; ++u) qf[j * 8 + u] = bf2f(qv[u]);
        }
    }

    float s[27];
    #pragma unroll
    for (int kk = 0; kk < 27; ++kk) {
        const int dz = kk / 9 - 1, dy = (kk / 3) % 3 - 1, dx = kk % 3 - 1;
        int nz = z + dz * r, ny = y + dy * r, nx = x + dx * r;
        bool ok = ((unsigned)nz < 32u) & ((unsigned)ny < 32u) & ((unsigned)nx < 32u);
        int nv = ok ? v + r * ((dz << 10) + (dy << 5) + dx) : v;
        const short8* kp = reinterpret_cast<const short8*>(kb + (size_t)nv * 32);
        float d = 0.f;
        #pragma unroll
        for (int j = 0; j < 2; ++j) {
            short8 kv = kp[j];
            #pragma unroll
            for (int u = 0; u < 8; ++u) d += qf[j * 8 + u] * bf2f(kv[u]);
        }
        d += __shfl_xor(d, 1);
        s[kk] = ok ? d * SCALE : 0.f;
    }

    float mx = s[0];
    #pragma unroll
    for (int kk = 1; kk < 27; ++kk) mx = fmaxf(mx, s[kk]);

    float o[16];
    #pragma unroll
    for (int c = 0; c < 16; ++c) o[c] = 0.f;
    float denom = 0.f;
    #pragma unroll
    for (int kk = 0; kk < 27; ++kk) {
        const int dz = kk / 9 - 1, dy = (kk / 3) % 3 - 1, dx = kk % 3 - 1;
        int nz = z + dz * r, ny = y + dy * r, nx = x + dx * r;
        bool ok = ((unsigned)nz < 32u) & ((unsigned)ny < 32u) & ((unsigned)nx < 32u);
        int nv = ok ? v + r * ((dz << 10) + (dy << 5) + dx) : v;
        float p = __expf(s[kk] - mx);
        denom += p;
        float w = ok ? p : 0.f;
        const short8* vp = reinterpret_cast<const short8*>(vb + (size_t)nv * 32);
        #pragma unroll
        for (int j = 0; j < 2; ++j) {
            short8 vv = vp[j];
            #pragma unroll
            for (int u = 0; u < 8; ++u) o[j * 8 + u] += w * bf2f(vv[u]);
        }
    }
    float inv = 1.f / denom;

    bf16* op = attn_out + (size_t)v * 192 + di * 64 + (dh & 1) * 32 + co;
    #pragma unroll
    for (int j = 0; j < 2; ++j) {
        short8 st;
        #pragma unroll
        for (int u = 0; u < 8; ++u) st[u] = f2bfs(o[j * 8 + u] * inv);
        *reinterpret_cast<short8*>(op + j * 8) = st;
    }
}

// ---------------------------------------------------------------------------
extern "C" void kernel_launch(void* const* d_in, const int* in_sizes, int n_in,
                              void* d_out, int out_size, void* d_ws, size_t ws_size,
                              hipStream_t stream) {
    const float* x      = (const float*)d_in[0];
    const float* qkv_w  = (const float*)d_in[1];
    const float* proj_w = (const float*)d_in[2];
    const float* proj_b = (const float*)d_in[3];
    const float* g1     = (const float*)d_in[4];
    const float* be1    = (const float*)d_in[5];
    const float* g2     = (const float*)d_in[6];
    const float* be2    = (const float*)d_in[7];
    const float* w1     = (const float*)d_in[8];
    const float* b1     = (const float*)d_in[9];
    const float* w2     = (const float*)d_in[10];
    const float* b2     = (const float*)d_in[11];
    float* out = (float*)d_out;

    char* p = (char*)d_ws;
    bf16* h     = (bf16*)p;  p += (size_t)NV * 192 * 2;
    bf16* lnb   = (bf16*)p;  p += (size_t)NV * 192 * 2;
    bf16* qkvb  = (bf16*)p;  p += (size_t)NV * 576 * 2;
    bf16* attnb = (bf16*)p;  p += (size_t)NV * 192 * 2;
    bf16* tb    = qkvb;  // [NV][768] overlaps dead qkvb+attnb exactly
    bf16* wqkv  = (bf16*)p;  p += (size_t)576 * 192 * 2;
    bf16* wproj = (bf16*)p;  p += (size_t)192 * 192 * 2;
    bf16* w1t   = (bf16*)p;  p += (size_t)768 * 192 * 2;
    bf16* w2t   = (bf16*)p;  p += (size_t)192 * 768 * 2;

    bf16* qa = qkvb;
    bf16* ka = qkvb + (size_t)6 * NV * 32;
    bf16* va = qkvb + (size_t)12 * NV * 32;

    // weight prep (1 launch) + fused transpose-in/LN1
    prep_kernel<<<(442368 + 255) / 256, 256, 0, stream>>>(
        qkv_w, proj_w, w1, w2, wqkv, wproj, w1t, w2t);
    tin_ln_kernel<<<1024, 256, 0, stream>>>(x, g1, be1, h, lnb);

    // QKV (scatter to attn layout) -> attn -> fused proj+res+LN2
    mgemm_kernel<3><<<dim3(NV / 128, 576 / 64), 256, 0, stream>>>(
        lnb, wqkv, qkvb, nullptr, nullptr, NV, 576, 192);
    attn_kernel<<<dim3(256, 6), 256, 0, stream>>>(qa, ka, va, attnb);
    projln_kernel<<<NV / 64, 256, 0, stream>>>(
        attnb, wproj, h, lnb, proj_b, g2, be2);

    // MLP: fc1 (GELU) -> fc2 (+res, in-place h)
    mgemm_kernel<2><<<dim3(NV / 128, HIDDEN / 64), 256, 0, stream>>>(
        lnb, w1t, tb, b1, nullptr, NV, HIDDEN, 192);
    mgemm_kernel<1><<<dim3(NV / 128, 192 / 64), 256, 0, stream>>>(
        tb, w2t, h, b2, h, NV, 192, HIDDEN);

    tout_kernel<<<1024, 256, 0, stream>>>(h, out);
}

// Round 7
// 150.009 us; speedup vs baseline: 2.2210x; 1.0756x over previous
//
#include <hip/hip_runtime.h>
#include <hip/hip_bf16.h>
#include <math.h>

#define NV     32768
#define HIDDEN 768
#define SCALE  0.17677669529663687f

typedef __attribute__((ext_vector_type(8))) short short8;
typedef __attribute__((ext_vector_type(4))) float floatx4;
typedef __hip_bfloat16 bf16;

__device__ __forceinline__ void gload16(const void* g, void* l) {
    __builtin_amdgcn_global_load_lds(
        (const __attribute__((address_space(1))) unsigned int*)g,
        (__attribute__((address_space(3))) unsigned int*)l, 16, 0, 0);
}

__device__ __forceinline__ float bf2f(short s) {
    unsigned u = ((unsigned)(unsigned short)s) << 16;
    return __builtin_bit_cast(float, u);
}
__device__ __forceinline__ short f2bfs(float f) {
    bf16 b = __float2bfloat16(f);
    return *reinterpret_cast<short*>(&b);
}

// ---------------------------------------------------------------------------
// All weight converts in one kernel.
__global__ __launch_bounds__(256) void prep_kernel(
        const float* __restrict__ qkv_w, const float* __restrict__ proj_w,
        const float* __restrict__ w1, const float* __restrict__ w2,
        bf16* __restrict__ wqkv, bf16* __restrict__ wproj,
        bf16* __restrict__ w1t, bf16* __restrict__ w2t) {
    int i = blockIdx.x * 256 + threadIdx.x;
    if (i < 110592) {
        wqkv[i] = (bf16)qkv_w[i];
    } else if (i < 147456) {
        int j = i - 110592; int r = j / 192, c = j - r * 192;
        wproj[c * 192 + r] = (bf16)proj_w[j];
    } else if (i < 294912) {
        int j = i - 147456; int r = j / 768, c = j - r * 768;
        w1t[c * 192 + r] = (bf16)w1[j];
    } else if (i < 442368) {
        int j = i - 294912; int r = j / 192, c = j - r * 192;
        w2t[c * 768 + r] = (bf16)w2[j];
    }
}

// ---------------------------------------------------------------------------
// Fused transpose-in + LN1: x[C,H,W,D] f32 -> h[v][192] bf16 (raw) + lnb bf16.
__global__ __launch_bounds__(256) void tin_ln_kernel(
        const float* __restrict__ xin, const float* __restrict__ g,
        const float* __restrict__ be, bf16* __restrict__ h,
        bf16* __restrict__ lnb) {
    __shared__ float lds[32 * 193];
    int yx = blockIdx.x;
    int y = yx >> 5, x = yx & 31;
    for (int idx = threadIdx.x; idx < 192 * 32; idx += 256) {
        int c = idx >> 5, z = idx & 31;
        lds[z * 193 + c] = xin[(((size_t)c * 32 + y) * 32 + x) * 32 + z];
    }
    __syncthreads();
    int wave = threadIdx.x >> 6, lane = threadIdx.x & 63;
    float ga = g[lane], gb = g[lane + 64], gc = g[lane + 128];
    float ba = be[lane], bb = be[lane + 64], bc = be[lane + 128];
    for (int z = wave; z < 32; z += 4) {
        float x0 = lds[z * 193 + lane];
        float x1 = lds[z * 193 + lane + 64];
        float x2 = lds[z * 193 + lane + 128];
        float s = x0 + x1 + x2;
        #pragma unroll
        for (int m = 32; m; m >>= 1) s += __shfl_xor(s, m);
        float mu = s * (1.f / 192.f);
        float d0 = x0 - mu, d1 = x1 - mu, d2 = x2 - mu;
        float s2 = d0 * d0 + d1 * d1 + d2 * d2;
        #pragma unroll
        for (int m = 32; m; m >>= 1) s2 += __shfl_xor(s2, m);
        float rstd = rsqrtf(s2 * (1.f / 192.f) + 1e-5f);
        size_t v = (size_t)((z << 10) + (y << 5) + x) * 192;
        h[v + lane]         = (bf16)x0;
        h[v + lane + 64]    = (bf16)x1;
        h[v + lane + 128]   = (bf16)x2;
        lnb[v + lane]       = (bf16)(d0 * rstd * ga + ba);
        lnb[v + lane + 64]  = (bf16)(d1 * rstd * gb + bb);
        lnb[v + lane + 128] = (bf16)(d2 * rstd * gc + bc);
    }
}

// Transpose out: h[v][C] bf16 -> out[C,H,W,D] f32
__global__ __launch_bounds__(256) void tout_kernel(const bf16* __restrict__ h,
                                                   float* __restrict__ outp) {
    __shared__ float lds[32 * 193];
    int yx = blockIdx.x;
    int y = yx >> 5, x = yx & 31;
    for (int idx = threadIdx.x; idx < 32 * 192; idx += 256) {
        int z = idx / 192, c = idx - z * 192;
        lds[z * 193 + c] = __bfloat162float(h[((size_t)((z * 32 + y) * 32 + x)) * 192 + c]);
    }
    __syncthreads();
    for (int idx = threadIdx.x; idx < 192 * 32; idx += 256) {
        int c = idx >> 5, z = idx & 31;
        outp[(((size_t)c * 32 + y) * 32 + x) * 32 + z] = lds[z * 193 + c];
    }
}

// ---------------------------------------------------------------------------
// bf16 MFMA GEMM: C = epi(A[M,K] @ Bw[N,K]^T). 128x64 tile, BK=64, 4 waves.
template <int MODE>
__global__ __launch_bounds__(256, 2) void mgemm_kernel(
        const bf16* __restrict__ A,
        const bf16* __restrict__ Bw,
        void* __restrict__ Cp,
        const float* __restrict__ bias,
        const bf16* __restrict__ res,
        int M, int N, int K) {
    __shared__ short Asm[128 * 64];
    __shared__ short Bsm[64 * 64];
    const int tid = threadIdx.x;
    const int lane = tid & 63;
    const int wave = tid >> 6;
    const int wm = wave >> 1, wn = wave & 1;
    const int m0 = blockIdx.x * 128;
    const int n0 = blockIdx.y * 64;

    const int srow = lane >> 3;
    const int scol = ((lane & 7) ^ ((lane >> 3) & 7)) * 16;

    floatx4 acc[4][2] = {};

    for (int k0 = 0; k0 < K; k0 += 64) {
        #pragma unroll
        for (int s = 0; s < 4; ++s) {
            int seg = wave * 4 + s;
            const char* g = (const char*)(A + (size_t)(m0 + seg * 8 + srow) * K + k0) + scol;
            gload16(g, (char*)Asm + seg * 1024);
        }
        #pragma unroll
        for (int s = 0; s < 2; ++s) {
            int seg = wave * 2 + s;
            const char* g = (const char*)(Bw + (size_t)(n0 + seg * 8 + srow) * K + k0) + scol;
            gload16(g, (char*)Bsm + seg * 1024);
        }
        __syncthreads();
        #pragma unroll
        for (int ks = 0; ks < 2; ++ks) {
            short8 af[4], bfr[2];
            const int cb = ks * 64 + (lane >> 4) * 16;
            #pragma unroll
            for (int i = 0; i < 4; ++i) {
                int row = wm * 64 + i * 16 + (lane & 15);
                af[i] = *reinterpret_cast<const short8*>(
                    (const char*)Asm + row * 128 + (cb ^ ((row & 7) << 4)));
            }
            #pragma unroll
            for (int j = 0; j < 2; ++j) {
                int row = wn * 32 + j * 16 + (lane & 15);
                bfr[j] = *reinterpret_cast<const short8*>(
                    (const char*)Bsm + row * 128 + (cb ^ ((row & 7) << 4)));
            }
            #pragma unroll
            for (int i = 0; i < 4; ++i)
                #pragma unroll
                for (int j = 0; j < 2; ++j)
                    acc[i][j] = __builtin_amdgcn_mfma_f32_16x16x32_bf16(
                        af[i], bfr[j], acc[i][j], 0, 0, 0);
        }
        __syncthreads();
    }

    const int r4 = (lane >> 4) * 4;
    const int cc = lane & 15;
    #pragma unroll
    for (int i = 0; i < 4; ++i) {
        #pragma unroll
        for (int j = 0; j < 2; ++j) {
            int colg = n0 + wn * 32 + j * 16 + cc;
            float bv = (MODE == 1 || MODE == 2) ? bias[colg] : 0.f;
            #pragma unroll
            for (int rg = 0; rg < 4; ++rg) {
                int rowg = m0 + wm * 64 + i * 16 + r4 + rg;
                float v = acc[i][j][rg];
                if (MODE == 1 || MODE == 2) v += bv;
                if (MODE == 2) v = 0.5f * v * (1.f + erff(v * 0.70710678118654752f));
                if (MODE == 1) {
                    v += __bfloat162float(res[(size_t)rowg * N + colg]);
                    ((bf16*)Cp)[(size_t)rowg * N + colg] = (bf16)v;
                } else if (MODE == 2) {
                    ((bf16*)Cp)[(size_t)rowg * N + colg] = (bf16)v;
                } else {  // MODE 3: part/di/h scatter
                    int part = colg / 192;
                    int rem  = colg - part * 192;
                    int di   = rem >> 6, hc = rem & 63;
                    size_t addr = (size_t)part * (6 * (size_t)NV * 32)
                                + (size_t)((di << 1) + (hc >> 5)) * ((size_t)NV * 32)
                                + (size_t)rowg * 32 + (hc & 31);
                    ((bf16*)Cp)[addr] = (bf16)v;
                }
            }
        }
    }
}

// ---------------------------------------------------------------------------
// Fused proj GEMM + residual + LN2 (unchanged from round 6).
__global__ __launch_bounds__(256) void projln_kernel(
        const bf16* __restrict__ A, const bf16* __restrict__ Bw,
        bf16* __restrict__ hres, bf16* __restrict__ lnout,
        const float* __restrict__ bias,
        const float* __restrict__ g2, const float* __restrict__ be2) {
    __shared__ short Asm[64 * 64];
    __shared__ short Bsm[192 * 64];
    const int tid = threadIdx.x;
    const int lane = tid & 63;
    const int wave = tid >> 6;
    const int m0 = blockIdx.x * 64;

    const int srow = lane >> 3;
    const int scol = ((lane & 7) ^ ((lane >> 3) & 7)) * 16;

    floatx4 acc[12] = {};

    for (int k0 = 0; k0 < 192; k0 += 64) {
        #pragma unroll
        for (int s = 0; s < 2; ++s) {
            int seg = wave * 2 + s;
            const char* g = (const char*)(A + (size_t)(m0 + seg * 8 + srow) * 192 + k0) + scol;
            gload16(g, (char*)Asm + seg * 1024);
        }
        #pragma unroll
        for (int s = 0; s < 6; ++s) {
            int seg = wave * 6 + s;
            const char* g = (const char*)(Bw + (size_t)(seg * 8 + srow) * 192 + k0) + scol;
            gload16(g, (char*)Bsm + seg * 1024);
        }
        __syncthreads();
        #pragma unroll
        for (int ks = 0; ks < 2; ++ks) {
            const int cb = ks * 64 + (lane >> 4) * 16;
            int arow = wave * 16 + (lane & 15);
            short8 af = *reinterpret_cast<const short8*>(
                (const char*)Asm + arow * 128 + (cb ^ ((arow & 7) << 4)));
            #pragma unroll
            for (int j = 0; j < 12; ++j) {
                int brow = j * 16 + (lane & 15);
                short8 bfr = *reinterpret_cast<const short8*>(
                    (const char*)Bsm + brow * 128 + (cb ^ ((brow & 7) << 4)));
                acc[j] = __builtin_amdgcn_mfma_f32_16x16x32_bf16(af, bfr, acc[j], 0, 0, 0);
            }
        }
        __syncthreads();
    }

    const int cc = lane & 15;
    #pragma unroll
    for (int rg = 0; rg < 4; ++rg) {
        int rowg = m0 + wave * 16 + (lane >> 4) * 4 + rg;
        float vals[12];
        float vsum = 0.f;
        #pragma unroll
        for (int j = 0; j < 12; ++j) {
            int col = j * 16 + cc;
            float v = acc[j][rg] + bias[col]
                    + __bfloat162float(hres[(size_t)rowg * 192 + col]);
            vals[j] = v;
            vsum += v;
        }
        #pragma unroll
        for (int m = 8; m; m >>= 1) vsum += __shfl_xor(vsum, m);
        float mu = vsum * (1.f / 192.f);
        float vsq = 0.f;
        #pragma unroll
        for (int j = 0; j < 12; ++j) {
            float d = vals[j] - mu;
            vsq += d * d;
        }
        #pragma unroll
        for (int m = 8; m; m >>= 1) vsq += __shfl_xor(vsq, m);
        float rstd = rsqrtf(vsq * (1.f / 192.f) + 1e-5f);
        #pragma unroll
        for (int j = 0; j < 12; ++j) {
            int col = j * 16 + cc;
            hres[(size_t)rowg * 192 + col] = (bf16)vals[j];
            lnout[(size_t)rowg * 192 + col] =
                (bf16)((vals[j] - mu) * rstd * g2[col] + be2[col]);
        }
    }
}

// ---------------------------------------------------------------------------
// Attention v3: half-voxel per lane, SINGLE-PASS softmax (no max subtraction —
// scores here are |s| << 1, so exp(s)/sum(exp) is exact & safe), plus
// XCD-chunked block swizzle: each XCD gets 192 contiguous blocks (~one dh x
// 24 z-planes ~ 5.3 MB K/V/Q working set ~ L2-resident).
// OOB taps: p=exp(0)=1 in denom, weight 0 (matches zero-padded reference).
__global__ __launch_bounds__(256) void attn_kernel(
        const bf16* __restrict__ qa,
        const bf16* __restrict__ ka,
        const bf16* __restrict__ va,
        bf16* __restrict__ attn_out) {
    const int lin = blockIdx.x;                    // 0..1535
    const int swz = (lin & 7) * 192 + (lin >> 3);  // XCD-contiguous chunks
    const int dh  = swz >> 8;
    const int yzg = swz & 255;
    const int di = dh >> 1;
    const int r  = di + 1;
    const int wave = threadIdx.x >> 6, lane = threadIdx.x & 63;
    const int yz = yzg * 4 + wave;
    const int z = yz >> 5, y = yz & 31;
    const int x = lane >> 1;
    const int v = (z << 10) + (y << 5) + x;
    const int co = (lane & 1) << 4;

    const bf16* qb = qa + (size_t)dh * NV * 32 + co;
    const bf16* kb = ka + (size_t)dh * NV * 32 + co;
    const bf16* vb = va + (size_t)dh * NV * 32 + co;

    float qf[16];
    {
        const short8* qp = reinterpret_cast<const short8*>(qb + (size_t)v * 32);
        #pragma unroll
        for (int j = 0; j < 2; ++j) {
            short8 qv = qp[j];
            #pragma unroll
            for (int u = 0; u < 8; ++u) qf[j * 8 + u] = bf2f(qv[u]);
        }
    }

    float o[16];
    #pragma unroll
    for (int c = 0; c < 16; ++c) o[c] = 0.f;
    float denom = 0.f;
    const float cexp = SCALE * 1.44269504088896f;  // fold log2(e) into scale

    #pragma unroll
    for (int kk = 0; kk < 27; ++kk) {
        const int dz = kk / 9 - 1, dy = (kk / 3) % 3 - 1, dx = kk % 3 - 1;
        int nz = z + dz * r, ny = y + dy * r, nx = x + dx * r;
        bool ok = ((unsigned)nz < 32u) & ((unsigned)ny < 32u) & ((unsigned)nx < 32u);
        int nv = ok ? v + r * ((dz << 10) + (dy << 5) + dx) : v;
        const short8* kp = reinterpret_cast<const short8*>(kb + (size_t)nv * 32);
        const short8* vp = reinterpret_cast<const short8*>(vb + (size_t)nv * 32);
        short8 k0 = kp[0], k1 = kp[1];
        short8 v0 = vp[0], v1 = vp[1];
        float d = 0.f;
        #pragma unroll
        for (int u = 0; u < 8; ++u) {
            d += qf[u]     * bf2f(k0[u]);
            d += qf[u + 8] * bf2f(k1[u]);
        }
        d += __shfl_xor(d, 1);                    // combine half-voxels
        float p = exp2f(ok ? d * cexp : 0.f);
        denom += p;
        float w = ok ? p : 0.f;
        #pragma unroll
        for (int u = 0; u < 8; ++u) {
            o[u]     += w * bf2f(v0[u]);
            o[u + 8] += w * bf2f(v1[u]);
        }
    }
    float inv = 1.f / denom;

    bf16* op = attn_out + (size_t)v * 192 + di * 64 + (dh & 1) * 32 + co;
    #pragma unroll
    for (int j = 0; j < 2; ++j) {
        short8 st;
        #pragma unroll
        for (int u = 0; u < 8; ++u) st[u] = f2bfs(o[j * 8 + u] * inv);
        *reinterpret_cast<short8*>(op + j * 8) = st;
    }
}

// ---------------------------------------------------------------------------
extern "C" void kernel_launch(void* const* d_in, const int* in_sizes, int n_in,
                              void* d_out, int out_size, void* d_ws, size_t ws_size,
                              hipStream_t stream) {
    const float* x      = (const float*)d_in[0];
    const float* qkv_w  = (const float*)d_in[1];
    const float* proj_w = (const float*)d_in[2];
    const float* proj_b = (const float*)d_in[3];
    const float* g1     = (const float*)d_in[4];
    const float* be1    = (const float*)d_in[5];
    const float* g2     = (const float*)d_in[6];
    const float* be2    = (const float*)d_in[7];
    const float* w1     = (const float*)d_in[8];
    const float* b1     = (const float*)d_in[9];
    const float* w2     = (const float*)d_in[10];
    const float* b2     = (const float*)d_in[11];
    float* out = (float*)d_out;

    char* p = (char*)d_ws;
    bf16* h     = (bf16*)p;  p += (size_t)NV * 192 * 2;
    bf16* lnb   = (bf16*)p;  p += (size_t)NV * 192 * 2;
    bf16* qkvb  = (bf16*)p;  p += (size_t)NV * 576 * 2;
    bf16* attnb = (bf16*)p;  p += (size_t)NV * 192 * 2;
    bf16* tb    = qkvb;  // [NV][768] overlaps dead qkvb+attnb exactly
    bf16* wqkv  = (bf16*)p;  p += (size_t)576 * 192 * 2;
    bf16* wproj = (bf16*)p;  p += (size_t)192 * 192 * 2;
    bf16* w1t   = (bf16*)p;  p += (size_t)768 * 192 * 2;
    bf16* w2t   = (bf16*)p;  p += (size_t)192 * 768 * 2;

    bf16* qa = qkvb;
    bf16* ka = qkvb + (size_t)6 * NV * 32;
    bf16* va = qkvb + (size_t)12 * NV * 32;

    prep_kernel<<<(442368 + 255) / 256, 256, 0, stream>>>(
        qkv_w, proj_w, w1, w2, wqkv, wproj, w1t, w2t);
    tin_ln_kernel<<<1024, 256, 0, stream>>>(x, g1, be1, h, lnb);

    mgemm_kernel<3><<<dim3(NV / 128, 576 / 64), 256, 0, stream>>>(
        lnb, wqkv, qkvb, nullptr, nullptr, NV, 576, 192);
    attn_kernel<<<1536, 256, 0, stream>>>(qa, ka, va, attnb);
    projln_kernel<<<NV / 64, 256, 0, stream>>>(
        attnb, wproj, h, lnb, proj_b, g2, be2);

    mgemm_kernel<2><<<dim3(NV / 128, HIDDEN / 64), 256, 0, stream>>>(
        lnb, w1t, tb, b1, nullptr, NV, HIDDEN, 192);
    mgemm_kernel<1><<<dim3(NV / 128, 192 / 64), 256, 0, stream>>>(
        tb, w2t, h, b2, h, NV, 192, HIDDEN);

    tout_kernel<<<1024, 256, 0, stream>>>(h, out);
}

// Round 8
// 149.767 us; speedup vs baseline: 2.2246x; 1.0016x over previous
//
#include <hip/hip_runtime.h>
#include <hip/hip_bf16.h>
#include <math.h>

#define NV     32768
#define HIDDEN 768
#define SCALE  0.17677669529663687f

typedef __attribute__((ext_vector_type(8))) short short8;
typedef __attribute__((ext_vector_type(4))) float floatx4;
typedef __hip_bfloat16 bf16;

__device__ __forceinline__ void gload16(const void* g, void* l) {
    __builtin_amdgcn_global_load_lds(
        (const __attribute__((address_space(1))) unsigned int*)g,
        (__attribute__((address_space(3))) unsigned int*)l, 16, 0, 0);
}

__device__ __forceinline__ float bf2f(short s) {
    unsigned u = ((unsigned)(unsigned short)s) << 16;
    return __builtin_bit_cast(float, u);
}
__device__ __forceinline__ short f2bfs(float f) {
    bf16 b = __float2bfloat16(f);
    return *reinterpret_cast<short*>(&b);
}

// ---------------------------------------------------------------------------
// All weight converts in one kernel.
__global__ __launch_bounds__(256) void prep_kernel(
        const float* __restrict__ qkv_w, const float* __restrict__ proj_w,
        const float* __restrict__ w1, const float* __restrict__ w2,
        bf16* __restrict__ wqkv, bf16* __restrict__ wproj,
        bf16* __restrict__ w1t, bf16* __restrict__ w2t) {
    int i = blockIdx.x * 256 + threadIdx.x;
    if (i < 110592) {
        wqkv[i] = (bf16)qkv_w[i];
    } else if (i < 147456) {
        int j = i - 110592; int r = j / 192, c = j - r * 192;
        wproj[c * 192 + r] = (bf16)proj_w[j];
    } else if (i < 294912) {
        int j = i - 147456; int r = j / 768, c = j - r * 768;
        w1t[c * 192 + r] = (bf16)w1[j];
    } else if (i < 442368) {
        int j = i - 294912; int r = j / 192, c = j - r * 192;
        w2t[c * 768 + r] = (bf16)w2[j];
    }
}

// ---------------------------------------------------------------------------
// Fused transpose-in + LN1: x[C,H,W,D] f32 -> h[v][192] bf16 (raw) + lnb bf16.
__global__ __launch_bounds__(256) void tin_ln_kernel(
        const float* __restrict__ xin, const float* __restrict__ g,
        const float* __restrict__ be, bf16* __restrict__ h,
        bf16* __restrict__ lnb) {
    __shared__ float lds[32 * 193];
    int yx = blockIdx.x;
    int y = yx >> 5, x = yx & 31;
    for (int idx = threadIdx.x; idx < 192 * 32; idx += 256) {
        int c = idx >> 5, z = idx & 31;
        lds[z * 193 + c] = xin[(((size_t)c * 32 + y) * 32 + x) * 32 + z];
    }
    __syncthreads();
    int wave = threadIdx.x >> 6, lane = threadIdx.x & 63;
    float ga = g[lane], gb = g[lane + 64], gc = g[lane + 128];
    float ba = be[lane], bb = be[lane + 64], bc = be[lane + 128];
    for (int z = wave; z < 32; z += 4) {
        float x0 = lds[z * 193 + lane];
        float x1 = lds[z * 193 + lane + 64];
        float x2 = lds[z * 193 + lane + 128];
        float s = x0 + x1 + x2;
        #pragma unroll
        for (int m = 32; m; m >>= 1) s += __shfl_xor(s, m);
        float mu = s * (1.f / 192.f);
        float d0 = x0 - mu, d1 = x1 - mu, d2 = x2 - mu;
        float s2 = d0 * d0 + d1 * d1 + d2 * d2;
        #pragma unroll
        for (int m = 32; m; m >>= 1) s2 += __shfl_xor(s2, m);
        float rstd = rsqrtf(s2 * (1.f / 192.f) + 1e-5f);
        size_t v = (size_t)((z << 10) + (y << 5) + x) * 192;
        h[v + lane]         = (bf16)x0;
        h[v + lane + 64]    = (bf16)x1;
        h[v + lane + 128]   = (bf16)x2;
        lnb[v + lane]       = (bf16)(d0 * rstd * ga + ba);
        lnb[v + lane + 64]  = (bf16)(d1 * rstd * gb + bb);
        lnb[v + lane + 128] = (bf16)(d2 * rstd * gc + bc);
    }
}

// Transpose out: h[v][C] bf16 -> out[C,H,W,D] f32
__global__ __launch_bounds__(256) void tout_kernel(const bf16* __restrict__ h,
                                                   float* __restrict__ outp) {
    __shared__ float lds[32 * 193];
    int yx = blockIdx.x;
    int y = yx >> 5, x = yx & 31;
    for (int idx = threadIdx.x; idx < 32 * 192; idx += 256) {
        int z = idx / 192, c = idx - z * 192;
        lds[z * 193 + c] = __bfloat162float(h[((size_t)((z * 32 + y) * 32 + x)) * 192 + c]);
    }
    __syncthreads();
    for (int idx = threadIdx.x; idx < 192 * 32; idx += 256) {
        int c = idx >> 5, z = idx & 31;
        outp[(((size_t)c * 32 + y) * 32 + x) * 32 + z] = lds[z * 193 + c];
    }
}

// ---------------------------------------------------------------------------
// bf16 MFMA GEMM: C = epi(A[M,K] @ Bw[N,K]^T). 128x64 tile, BK=64, 4 waves.
template <int MODE>
__global__ __launch_bounds__(256, 2) void mgemm_kernel(
        const bf16* __restrict__ A,
        const bf16* __restrict__ Bw,
        void* __restrict__ Cp,
        const float* __restrict__ bias,
        const bf16* __restrict__ res,
        int M, int N, int K) {
    __shared__ short Asm[128 * 64];
    __shared__ short Bsm[64 * 64];
    const int tid = threadIdx.x;
    const int lane = tid & 63;
    const int wave = tid >> 6;
    const int wm = wave >> 1, wn = wave & 1;
    const int m0 = blockIdx.x * 128;
    const int n0 = blockIdx.y * 64;

    const int srow = lane >> 3;
    const int scol = ((lane & 7) ^ ((lane >> 3) & 7)) * 16;

    floatx4 acc[4][2] = {};

    for (int k0 = 0; k0 < K; k0 += 64) {
        #pragma unroll
        for (int s = 0; s < 4; ++s) {
            int seg = wave * 4 + s;
            const char* g = (const char*)(A + (size_t)(m0 + seg * 8 + srow) * K + k0) + scol;
            gload16(g, (char*)Asm + seg * 1024);
        }
        #pragma unroll
        for (int s = 0; s < 2; ++s) {
            int seg = wave * 2 + s;
            const char* g = (const char*)(Bw + (size_t)(n0 + seg * 8 + srow) * K + k0) + scol;
            gload16(g, (char*)Bsm + seg * 1024);
        }
        __syncthreads();
        #pragma unroll
        for (int ks = 0; ks < 2; ++ks) {
            short8 af[4], bfr[2];
            const int cb = ks * 64 + (lane >> 4) * 16;
            #pragma unroll
            for (int i = 0; i < 4; ++i) {
                int row = wm * 64 + i * 16 + (lane & 15);
                af[i] = *reinterpret_cast<const short8*>(
                    (const char*)Asm + row * 128 + (cb ^ ((row & 7) << 4)));
            }
            #pragma unroll
            for (int j = 0; j < 2; ++j) {
                int row = wn * 32 + j * 16 + (lane & 15);
                bfr[j] = *reinterpret_cast<const short8*>(
                    (const char*)Bsm + row * 128 + (cb ^ ((row & 7) << 4)));
            }
            #pragma unroll
            for (int i = 0; i < 4; ++i)
                #pragma unroll
                for (int j = 0; j < 2; ++j)
                    acc[i][j] = __builtin_amdgcn_mfma_f32_16x16x32_bf16(
                        af[i], bfr[j], acc[i][j], 0, 0, 0);
        }
        __syncthreads();
    }

    const int r4 = (lane >> 4) * 4;
    const int cc = lane & 15;
    #pragma unroll
    for (int i = 0; i < 4; ++i) {
        #pragma unroll
        for (int j = 0; j < 2; ++j) {
            int colg = n0 + wn * 32 + j * 16 + cc;
            float bv = (MODE == 1 || MODE == 2) ? bias[colg] : 0.f;
            #pragma unroll
            for (int rg = 0; rg < 4; ++rg) {
                int rowg = m0 + wm * 64 + i * 16 + r4 + rg;
                float v = acc[i][j][rg];
                if (MODE == 1 || MODE == 2) v += bv;
                if (MODE == 2) v = 0.5f * v * (1.f + erff(v * 0.70710678118654752f));
                if (MODE == 1) {
                    v += __bfloat162float(res[(size_t)rowg * N + colg]);
                    ((bf16*)Cp)[(size_t)rowg * N + colg] = (bf16)v;
                } else if (MODE == 2) {
                    ((bf16*)Cp)[(size_t)rowg * N + colg] = (bf16)v;
                } else {  // MODE 3: part/di/h scatter
                    int part = colg / 192;
                    int rem  = colg - part * 192;
                    int di   = rem >> 6, hc = rem & 63;
                    size_t addr = (size_t)part * (6 * (size_t)NV * 32)
                                + (size_t)((di << 1) + (hc >> 5)) * ((size_t)NV * 32)
                                + (size_t)rowg * 32 + (hc & 31);
                    ((bf16*)Cp)[addr] = (bf16)v;
                }
            }
        }
    }
}

// ---------------------------------------------------------------------------
// Fused proj GEMM + residual + LN2 (unchanged).
__global__ __launch_bounds__(256) void projln_kernel(
        const bf16* __restrict__ A, const bf16* __restrict__ Bw,
        bf16* __restrict__ hres, bf16* __restrict__ lnout,
        const float* __restrict__ bias,
        const float* __restrict__ g2, const float* __restrict__ be2) {
    __shared__ short Asm[64 * 64];
    __shared__ short Bsm[192 * 64];
    const int tid = threadIdx.x;
    const int lane = tid & 63;
    const int wave = tid >> 6;
    const int m0 = blockIdx.x * 64;

    const int srow = lane >> 3;
    const int scol = ((lane & 7) ^ ((lane >> 3) & 7)) * 16;

    floatx4 acc[12] = {};

    for (int k0 = 0; k0 < 192; k0 += 64) {
        #pragma unroll
        for (int s = 0; s < 2; ++s) {
            int seg = wave * 2 + s;
            const char* g = (const char*)(A + (size_t)(m0 + seg * 8 + srow) * 192 + k0) + scol;
            gload16(g, (char*)Asm + seg * 1024);
        }
        #pragma unroll
        for (int s = 0; s < 6; ++s) {
            int seg = wave * 6 + s;
            const char* g = (const char*)(Bw + (size_t)(seg * 8 + srow) * 192 + k0) + scol;
            gload16(g, (char*)Bsm + seg * 1024);
        }
        __syncthreads();
        #pragma unroll
        for (int ks = 0; ks < 2; ++ks) {
            const int cb = ks * 64 + (lane >> 4) * 16;
            int arow = wave * 16 + (lane & 15);
            short8 af = *reinterpret_cast<const short8*>(
                (const char*)Asm + arow * 128 + (cb ^ ((arow & 7) << 4)));
            #pragma unroll
            for (int j = 0; j < 12; ++j) {
                int brow = j * 16 + (lane & 15);
                short8 bfr = *reinterpret_cast<const short8*>(
                    (const char*)Bsm + brow * 128 + (cb ^ ((brow & 7) << 4)));
                acc[j] = __builtin_amdgcn_mfma_f32_16x16x32_bf16(af, bfr, acc[j], 0, 0, 0);
            }
        }
        __syncthreads();
    }

    const int cc = lane & 15;
    #pragma unroll
    for (int rg = 0; rg < 4; ++rg) {
        int rowg = m0 + wave * 16 + (lane >> 4) * 4 + rg;
        float vals[12];
        float vsum = 0.f;
        #pragma unroll
        for (int j = 0; j < 12; ++j) {
            int col = j * 16 + cc;
            float v = acc[j][rg] + bias[col]
                    + __bfloat162float(hres[(size_t)rowg * 192 + col]);
            vals[j] = v;
            vsum += v;
        }
        #pragma unroll
        for (int m = 8; m; m >>= 1) vsum += __shfl_xor(vsum, m);
        float mu = vsum * (1.f / 192.f);
        float vsq = 0.f;
        #pragma unroll
        for (int j = 0; j < 12; ++j) {
            float d = vals[j] - mu;
            vsq += d * d;
        }
        #pragma unroll
        for (int m = 8; m; m >>= 1) vsq += __shfl_xor(vsq, m);
        float rstd = rsqrtf(vsq * (1.f / 192.f) + 1e-5f);
        #pragma unroll
        for (int j = 0; j < 12; ++j) {
            int col = j * 16 + cc;
            hres[(size_t)rowg * 192 + col] = (bf16)vals[j];
            lnout[(size_t)rowg * 192 + col] =
                (bf16)((vals[j] - mu) * rstd * g2[col] + be2[col]);
        }
    }
}

// ---------------------------------------------------------------------------
// Attention v4: QUARTER-voxel per lane (8 ch). 4 lanes/voxel, wave = 16 vox.
// Single-pass softmax (|s| << 1); XCD-chunked swizzle (384 blocks/XCD).
// Block: 4 waves = 2 (z,y) rows. Grid: 512 row-pairs x 6 dh = 3072 blocks.
__global__ __launch_bounds__(256) void attn_kernel(
        const bf16* __restrict__ qa,
        const bf16* __restrict__ ka,
        const bf16* __restrict__ va,
        bf16* __restrict__ attn_out) {
    const int lin = blockIdx.x;                     // 0..3071
    const int swz = (lin & 7) * 384 + (lin >> 3);   // XCD-contiguous chunks
    const int dh  = swz >> 9;                       // 0..5
    const int rp  = swz & 511;                      // row-pair
    const int di = dh >> 1;
    const int r  = di + 1;
    const int wave = threadIdx.x >> 6, lane = threadIdx.x & 63;
    const int yz = rp * 2 + (wave >> 1);            // 0..1023
    const int z = yz >> 5, y = yz & 31;
    const int x = ((wave & 1) << 4) + (lane >> 2);
    const int co = (lane & 3) << 3;                 // 8-channel slice
    const int v = (z << 10) + (y << 5) + x;

    const bf16* qb = qa + (size_t)dh * NV * 32 + co;
    const bf16* kb = ka + (size_t)dh * NV * 32 + co;
    const bf16* vb = va + (size_t)dh * NV * 32 + co;

    float qf[8];
    {
        short8 qv = *reinterpret_cast<const short8*>(qb + (size_t)v * 32);
        #pragma unroll
        for (int u = 0; u < 8; ++u) qf[u] = bf2f(qv[u]);
    }

    float o[8];
    #pragma unroll
    for (int c = 0; c < 8; ++c) o[c] = 0.f;
    float denom = 0.f;
    const float cexp = SCALE * 1.44269504088896f;

    #pragma unroll
    for (int kk = 0; kk < 27; ++kk) {
        const int dz = kk / 9 - 1, dy = (kk / 3) % 3 - 1, dx = kk % 3 - 1;
        int nz = z + dz * r, ny = y + dy * r, nx = x + dx * r;
        bool ok = ((unsigned)nz < 32u) & ((unsigned)ny < 32u) & ((unsigned)nx < 32u);
        int nv = ok ? v + r * ((dz << 10) + (dy << 5) + dx) : v;
        short8 kv = *reinterpret_cast<const short8*>(kb + (size_t)nv * 32);
        short8 vv = *reinterpret_cast<const short8*>(vb + (size_t)nv * 32);
        float d = 0.f;
        #pragma unroll
        for (int u = 0; u < 8; ++u) d += qf[u] * bf2f(kv[u]);
        d += __shfl_xor(d, 1);
        d += __shfl_xor(d, 2);                      // full 32-ch dot
        float p = exp2f(ok ? d * cexp : 0.f);
        denom += p;
        float w = ok ? p : 0.f;
        #pragma unroll
        for (int u = 0; u < 8; ++u) o[u] += w * bf2f(vv[u]);
    }
    float inv = 1.f / denom;

    bf16* op = attn_out + (size_t)v * 192 + di * 64 + (dh & 1) * 32 + co;
    short8 st;
    #pragma unroll
    for (int u = 0; u < 8; ++u) st[u] = f2bfs(o[u] * inv);
    *reinterpret_cast<short8*>(op) = st;
}

// ---------------------------------------------------------------------------
extern "C" void kernel_launch(void* const* d_in, const int* in_sizes, int n_in,
                              void* d_out, int out_size, void* d_ws, size_t ws_size,
                              hipStream_t stream) {
    const float* x      = (const float*)d_in[0];
    const float* qkv_w  = (const float*)d_in[1];
    const float* proj_w = (const float*)d_in[2];
    const float* proj_b = (const float*)d_in[3];
    const float* g1     = (const float*)d_in[4];
    const float* be1    = (const float*)d_in[5];
    const float* g2     = (const float*)d_in[6];
    const float* be2    = (const float*)d_in[7];
    const float* w1     = (const float*)d_in[8];
    const float* b1     = (const float*)d_in[9];
    const float* w2     = (const float*)d_in[10];
    const float* b2     = (const float*)d_in[11];
    float* out = (float*)d_out;

    char* p = (char*)d_ws;
    bf16* h     = (bf16*)p;  p += (size_t)NV * 192 * 2;
    bf16* lnb   = (bf16*)p;  p += (size_t)NV * 192 * 2;
    bf16* qkvb  = (bf16*)p;  p += (size_t)NV * 576 * 2;
    bf16* attnb = (bf16*)p;  p += (size_t)NV * 192 * 2;
    bf16* tb    = qkvb;  // [NV][768] overlaps dead qkvb+attnb exactly
    bf16* wqkv  = (bf16*)p;  p += (size_t)576 * 192 * 2;
    bf16* wproj = (bf16*)p;  p += (size_t)192 * 192 * 2;
    bf16* w1t   = (bf16*)p;  p += (size_t)768 * 192 * 2;
    bf16* w2t   = (bf16*)p;  p += (size_t)192 * 768 * 2;

    bf16* qa = qkvb;
    bf16* ka = qkvb + (size_t)6 * NV * 32;
    bf16* va = qkvb + (size_t)12 * NV * 32;

    prep_kernel<<<(442368 + 255) / 256, 256, 0, stream>>>(
        qkv_w, proj_w, w1, w2, wqkv, wproj, w1t, w2t);
    tin_ln_kernel<<<1024, 256, 0, stream>>>(x, g1, be1, h, lnb);

    mgemm_kernel<3><<<dim3(NV / 128, 576 / 64), 256, 0, stream>>>(
        lnb, wqkv, qkvb, nullptr, nullptr, NV, 576, 192);
    attn_kernel<<<3072, 256, 0, stream>>>(qa, ka, va, attnb);
    projln_kernel<<<NV / 64, 256, 0, stream>>>(
        attnb, wproj, h, lnb, proj_b, g2, be2);

    mgemm_kernel<2><<<dim3(NV / 128, HIDDEN / 64), 256, 0, stream>>>(
        lnb, w1t, tb, b1, nullptr, NV, HIDDEN, 192);
    mgemm_kernel<1><<<dim3(NV / 128, 192 / 64), 256, 0, stream>>>(
        tb, w2t, h, b2, h, NV, 192, HIDDEN);

    tout_kernel<<<1024, 256, 0, stream>>>(h, out);
}

// Round 10
// 135.063 us; speedup vs baseline: 2.4668x; 1.1089x over previous
//
#include <hip/hip_runtime.h>
#include <hip/hip_bf16.h>
#include <math.h>

#define NV     32768
#define HIDDEN 768
#define SCALE  0.17677669529663687f

typedef __attribute__((ext_vector_type(8))) short short8;
typedef __attribute__((ext_vector_type(4))) float floatx4;
typedef __attribute__((ext_vector_type(8))) _Float16 h8;
typedef __attribute__((ext_vector_type(2))) _Float16 h2;
typedef __hip_bfloat16 bf16;

__device__ __forceinline__ void gload16(const void* g, void* l) {
    __builtin_amdgcn_global_load_lds(
        (const __attribute__((address_space(1))) unsigned int*)g,
        (__attribute__((address_space(3))) unsigned int*)l, 16, 0, 0);
}

__device__ __forceinline__ float bf2f(short s) {
    unsigned u = ((unsigned)(unsigned short)s) << 16;
    return __builtin_bit_cast(float, u);
}
__device__ __forceinline__ short f2bfs(float f) {
    bf16 b = __float2bfloat16(f);
    return *reinterpret_cast<short*>(&b);
}

// ---------------------------------------------------------------------------
// All weight converts in one kernel.
__global__ __launch_bounds__(256) void prep_kernel(
        const float* __restrict__ qkv_w, const float* __restrict__ proj_w,
        const float* __restrict__ w1, const float* __restrict__ w2,
        bf16* __restrict__ wqkv, bf16* __restrict__ wproj,
        bf16* __restrict__ w1t, bf16* __restrict__ w2t) {
    int i = blockIdx.x * 256 + threadIdx.x;
    if (i < 110592) {
        wqkv[i] = (bf16)qkv_w[i];
    } else if (i < 147456) {
        int j = i - 110592; int r = j / 192, c = j - r * 192;
        wproj[c * 192 + r] = (bf16)proj_w[j];
    } else if (i < 294912) {
        int j = i - 147456; int r = j / 768, c = j - r * 768;
        w1t[c * 192 + r] = (bf16)w1[j];
    } else if (i < 442368) {
        int j = i - 294912; int r = j / 192, c = j - r * 192;
        w2t[c * 768 + r] = (bf16)w2[j];
    }
}

// ---------------------------------------------------------------------------
// Fused transpose-in + LN1: x[C,H,W,D] f32 -> h[v][192] bf16 (raw) + lnb bf16.
__global__ __launch_bounds__(256) void tin_ln_kernel(
        const float* __restrict__ xin, const float* __restrict__ g,
        const float* __restrict__ be, bf16* __restrict__ h,
        bf16* __restrict__ lnb) {
    __shared__ float lds[32 * 193];
    int yx = blockIdx.x;
    int y = yx >> 5, x = yx & 31;
    for (int idx = threadIdx.x; idx < 192 * 32; idx += 256) {
        int c = idx >> 5, z = idx & 31;
        lds[z * 193 + c] = xin[(((size_t)c * 32 + y) * 32 + x) * 32 + z];
    }
    __syncthreads();
    int wave = threadIdx.x >> 6, lane = threadIdx.x & 63;
    float ga = g[lane], gb = g[lane + 64], gc = g[lane + 128];
    float ba = be[lane], bb = be[lane + 64], bc = be[lane + 128];
    for (int z = wave; z < 32; z += 4) {
        float x0 = lds[z * 193 + lane];
        float x1 = lds[z * 193 + lane + 64];
        float x2 = lds[z * 193 + lane + 128];
        float s = x0 + x1 + x2;
        #pragma unroll
        for (int m = 32; m; m >>= 1) s += __shfl_xor(s, m);
        float mu = s * (1.f / 192.f);
        float d0 = x0 - mu, d1 = x1 - mu, d2 = x2 - mu;
        float s2 = d0 * d0 + d1 * d1 + d2 * d2;
        #pragma unroll
        for (int m = 32; m; m >>= 1) s2 += __shfl_xor(s2, m);
        float rstd = rsqrtf(s2 * (1.f / 192.f) + 1e-5f);
        size_t v = (size_t)((z << 10) + (y << 5) + x) * 192;
        h[v + lane]         = (bf16)x0;
        h[v + lane + 64]    = (bf16)x1;
        h[v + lane + 128]   = (bf16)x2;
        lnb[v + lane]       = (bf16)(d0 * rstd * ga + ba);
        lnb[v + lane + 64]  = (bf16)(d1 * rstd * gb + bb);
        lnb[v + lane + 128] = (bf16)(d2 * rstd * gc + bc);
    }
}

// Transpose out: h[v][C] bf16 -> out[C,H,W,D] f32
__global__ __launch_bounds__(256) void tout_kernel(const bf16* __restrict__ h,
                                                   float* __restrict__ outp) {
    __shared__ float lds[32 * 193];
    int yx = blockIdx.x;
    int y = yx >> 5, x = yx & 31;
    for (int idx = threadIdx.x; idx < 32 * 192; idx += 256) {
        int z = idx / 192, c = idx - z * 192;
        lds[z * 193 + c] = __bfloat162float(h[((size_t)((z * 32 + y) * 32 + x)) * 192 + c]);
    }
    __syncthreads();
    for (int idx = threadIdx.x; idx < 192 * 32; idx += 256) {
        int c = idx >> 5, z = idx & 31;
        outp[(((size_t)c * 32 + y) * 32 + x) * 32 + z] = lds[z * 193 + c];
    }
}

// ---------------------------------------------------------------------------
// bf16 MFMA GEMM. MODE 1: +bias +res -> bf16. MODE 2: +bias GELU -> bf16.
// MODE 3: scatter to attn layout as FP16.
template <int MODE>
__global__ __launch_bounds__(256, 2) void mgemm_kernel(
        const bf16* __restrict__ A,
        const bf16* __restrict__ Bw,
        void* __restrict__ Cp,
        const float* __restrict__ bias,
        const bf16* __restrict__ res,
        int M, int N, int K) {
    __shared__ short Asm[128 * 64];
    __shared__ short Bsm[64 * 64];
    const int tid = threadIdx.x;
    const int lane = tid & 63;
    const int wave = tid >> 6;
    const int wm = wave >> 1, wn = wave & 1;
    const int m0 = blockIdx.x * 128;
    const int n0 = blockIdx.y * 64;

    const int srow = lane >> 3;
    const int scol = ((lane & 7) ^ ((lane >> 3) & 7)) * 16;

    floatx4 acc[4][2] = {};

    for (int k0 = 0; k0 < K; k0 += 64) {
        #pragma unroll
        for (int s = 0; s < 4; ++s) {
            int seg = wave * 4 + s;
            const char* g = (const char*)(A + (size_t)(m0 + seg * 8 + srow) * K + k0) + scol;
            gload16(g, (char*)Asm + seg * 1024);
        }
        #pragma unroll
        for (int s = 0; s < 2; ++s) {
            int seg = wave * 2 + s;
            const char* g = (const char*)(Bw + (size_t)(n0 + seg * 8 + srow) * K + k0) + scol;
            gload16(g, (char*)Bsm + seg * 1024);
        }
        __syncthreads();
        #pragma unroll
        for (int ks = 0; ks < 2; ++ks) {
            short8 af[4], bfr[2];
            const int cb = ks * 64 + (lane >> 4) * 16;
            #pragma unroll
            for (int i = 0; i < 4; ++i) {
                int row = wm * 64 + i * 16 + (lane & 15);
                af[i] = *reinterpret_cast<const short8*>(
                    (const char*)Asm + row * 128 + (cb ^ ((row & 7) << 4)));
            }
            #pragma unroll
            for (int j = 0; j < 2; ++j) {
                int row = wn * 32 + j * 16 + (lane & 15);
                bfr[j] = *reinterpret_cast<const short8*>(
                    (const char*)Bsm + row * 128 + (cb ^ ((row & 7) << 4)));
            }
            #pragma unroll
            for (int i = 0; i < 4; ++i)
                #pragma unroll
                for (int j = 0; j < 2; ++j)
                    acc[i][j] = __builtin_amdgcn_mfma_f32_16x16x32_bf16(
                        af[i], bfr[j], acc[i][j], 0, 0, 0);
        }
        __syncthreads();
    }

    const int r4 = (lane >> 4) * 4;
    const int cc = lane & 15;
    #pragma unroll
    for (int i = 0; i < 4; ++i) {
        #pragma unroll
        for (int j = 0; j < 2; ++j) {
            int colg = n0 + wn * 32 + j * 16 + cc;
            float bv = (MODE == 1 || MODE == 2) ? bias[colg] : 0.f;
            #pragma unroll
            for (int rg = 0; rg < 4; ++rg) {
                int rowg = m0 + wm * 64 + i * 16 + r4 + rg;
                float v = acc[i][j][rg];
                if (MODE == 1 || MODE == 2) v += bv;
                if (MODE == 2) v = 0.5f * v * (1.f + erff(v * 0.70710678118654752f));
                if (MODE == 1) {
                    v += __bfloat162float(res[(size_t)rowg * N + colg]);
                    ((bf16*)Cp)[(size_t)rowg * N + colg] = (bf16)v;
                } else if (MODE == 2) {
                    ((bf16*)Cp)[(size_t)rowg * N + colg] = (bf16)v;
                } else {  // MODE 3: part/di/h scatter, FP16 output
                    int part = colg / 192;
                    int rem  = colg - part * 192;
                    int di   = rem >> 6, hc = rem & 63;
                    size_t addr = (size_t)part * (6 * (size_t)NV * 32)
                                + (size_t)((di << 1) + (hc >> 5)) * ((size_t)NV * 32)
                                + (size_t)rowg * 32 + (hc & 31);
                    ((_Float16*)Cp)[addr] = (_Float16)v;
                }
            }
        }
    }
}

// ---------------------------------------------------------------------------
// Fused proj GEMM + residual + LN2 (unchanged).
__global__ __launch_bounds__(256) void projln_kernel(
        const bf16* __restrict__ A, const bf16* __restrict__ Bw,
        bf16* __restrict__ hres, bf16* __restrict__ lnout,
        const float* __restrict__ bias,
        const float* __restrict__ g2, const float* __restrict__ be2) {
    __shared__ short Asm[64 * 64];
    __shared__ short Bsm[192 * 64];
    const int tid = threadIdx.x;
    const int lane = tid & 63;
    const int wave = tid >> 6;
    const int m0 = blockIdx.x * 64;

    const int srow = lane >> 3;
    const int scol = ((lane & 7) ^ ((lane >> 3) & 7)) * 16;

    floatx4 acc[12] = {};

    for (int k0 = 0; k0 < 192; k0 += 64) {
        #pragma unroll
        for (int s = 0; s < 2; ++s) {
            int seg = wave * 2 + s;
            const char* g = (const char*)(A + (size_t)(m0 + seg * 8 + srow) * 192 + k0) + scol;
            gload16(g, (char*)Asm + seg * 1024);
        }
        #pragma unroll
        for (int s = 0; s < 6; ++s) {
            int seg = wave * 6 + s;
            const char* g = (const char*)(Bw + (size_t)(seg * 8 + srow) * 192 + k0) + scol;
            gload16(g, (char*)Bsm + seg * 1024);
        }
        __syncthreads();
        #pragma unroll
        for (int ks = 0; ks < 2; ++ks) {
            const int cb = ks * 64 + (lane >> 4) * 16;
            int arow = wave * 16 + (lane & 15);
            short8 af = *reinterpret_cast<const short8*>(
                (const char*)Asm + arow * 128 + (cb ^ ((arow & 7) << 4)));
            #pragma unroll
            for (int j = 0; j < 12; ++j) {
                int brow = j * 16 + (lane & 15);
                short8 bfr = *reinterpret_cast<const short8*>(
                    (const char*)Bsm + brow * 128 + (cb ^ ((brow & 7) << 4)));
                acc[j] = __builtin_amdgcn_mfma_f32_16x16x32_bf16(af, bfr, acc[j], 0, 0, 0);
            }
        }
        __syncthreads();
    }

    const int cc = lane & 15;
    #pragma unroll
    for (int rg = 0; rg < 4; ++rg) {
        int rowg = m0 + wave * 16 + (lane >> 4) * 4 + rg;
        float vals[12];
        float vsum = 0.f;
        #pragma unroll
        for (int j = 0; j < 12; ++j) {
            int col = j * 16 + cc;
            float v = acc[j][rg] + bias[col]
                    + __bfloat162float(hres[(size_t)rowg * 192 + col]);
            vals[j] = v;
            vsum += v;
        }
        #pragma unroll
        for (int m = 8; m; m >>= 1) vsum += __shfl_xor(vsum, m);
        float mu = vsum * (1.f / 192.f);
        float vsq = 0.f;
        #pragma unroll
        for (int j = 0; j < 12; ++j) {
            float d = vals[j] - mu;
            vsq += d * d;
        }
        #pragma unroll
        for (int m = 8; m; m >>= 1) vsq += __shfl_xor(vsq, m);
        float rstd = rsqrtf(vsq * (1.f / 192.f) + 1e-5f);
        #pragma unroll
        for (int j = 0; j < 12; ++j) {
            int col = j * 16 + cc;
            hres[(size_t)rowg * 192 + col] = (bf16)vals[j];
            lnout[(size_t)rowg * 192 + col] =
                (bf16)((vals[j] - mu) * rstd * g2[col] + be2[col]);
        }
    }
}

// ---------------------------------------------------------------------------
// Attention v5b: fp16 + LDS row staging. Block = one (dh,z,y) x-row, 128 thr.
// lane t: voxel x = t>>2, c4 = t&3 (8 channels). LDS: 18 slots x 2KB
// (slot = tensor*9 + (dz+1)*3 + (dy+1)), each = one 32-vox row of 32ch fp16.
// FIX vs v5: OOB rows staged with CLAMPED coords (always finite data) — the
// ok-mask zeroes their weight, but 0*garbage-NaN previously poisoned PV.
__global__ __launch_bounds__(128) void attn_kernel(
        const _Float16* __restrict__ qa,
        const _Float16* __restrict__ ka,
        const _Float16* __restrict__ va,
        bf16* __restrict__ attn_out) {
    __shared__ _Float16 lds[18432];                 // 36 KB
    const int lin = blockIdx.x;                     // 0..6143
    const int swz = (lin & 7) * 768 + (lin >> 3);   // XCD-contiguous chunks
    const int dh  = swz >> 10;                      // 0..5
    const int yz  = swz & 1023;
    const int di = dh >> 1;
    const int r  = di + 1;
    const int z = yz >> 5, y = yz & 31;
    const int t = threadIdx.x;

    const _Float16* kb = ka + (size_t)dh * NV * 32;
    const _Float16* vb = va + (size_t)dh * NV * 32;

    // stage 9 K rows + 9 V rows (2 KB each); clamp coords so LDS is always
    // valid finite data (OOB taps are masked at use, but must not read NaN)
    #pragma unroll
    for (int s = 0; s < 18; ++s) {
        const int sr = s % 9;
        const int dz = sr / 3 - 1, dy = sr % 3 - 1;
        int zz = z + dz * r, yy = y + dy * r;
        zz = zz < 0 ? 0 : (zz > 31 ? 31 : zz);
        yy = yy < 0 ? 0 : (yy > 31 ? 31 : yy);
        const _Float16* src = (s < 9 ? kb : vb)
                            + (size_t)(((zz << 10) + (yy << 5)) * 32);
        gload16((const char*)src + t * 16,
                (char*)lds + s * 2048 + (t >> 6) * 1024);
    }

    const int x = t >> 2, c4 = t & 3;
    const int v = (z << 10) + (y << 5) + x;
    h8 q8 = *reinterpret_cast<const h8*>(qa + ((size_t)dh * NV + v) * 32 + c4 * 8);
    h2 q01 = {q8[0], q8[1]}, q23 = {q8[2], q8[3]};
    h2 q45 = {q8[4], q8[5]}, q67 = {q8[6], q8[7]};

    __syncthreads();

    float denom = 0.f;
    h2 o01 = {0, 0}, o23 = {0, 0}, o45 = {0, 0}, o67 = {0, 0};
    const float cexp = SCALE * 1.44269504088896f;

    #pragma unroll
    for (int kk = 0; kk < 27; ++kk) {
        const int dz = kk / 9 - 1, dy = (kk / 3) % 3 - 1, dx = kk % 3 - 1;
        const int slot = (dz + 1) * 3 + (dy + 1);
        int nz = z + dz * r, ny = y + dy * r, nx = x + dx * r;
        bool ok = ((unsigned)nz < 32u) & ((unsigned)ny < 32u) & ((unsigned)nx < 32u);
        int rx = ok ? nx : x;
        const char* kaddr = (const char*)lds + slot * 2048 + rx * 64 + c4 * 16;
        h8 k8 = *reinterpret_cast<const h8*>(kaddr);
        h8 v8 = *reinterpret_cast<const h8*>(kaddr + 9 * 2048);
        h2 a = q01 * (h2){k8[0], k8[1]};
        a = q23 * (h2){k8[2], k8[3]} + a;
        a = q45 * (h2){k8[4], k8[5]} + a;
        a = q67 * (h2){k8[6], k8[7]} + a;
        float d = (float)a[0] + (float)a[1];
        d += __shfl_xor(d, 1);
        d += __shfl_xor(d, 2);                      // full 32-ch dot
        float p = exp2f(ok ? d * cexp : 0.f);
        denom += p;
        float w = ok ? p : 0.f;
        _Float16 wh = (_Float16)w;
        h2 w2 = {wh, wh};
        o01 = w2 * (h2){v8[0], v8[1]} + o01;
        o23 = w2 * (h2){v8[2], v8[3]} + o23;
        o45 = w2 * (h2){v8[4], v8[5]} + o45;
        o67 = w2 * (h2){v8[6], v8[7]} + o67;
    }
    float inv = 1.f / denom;

    bf16* op = attn_out + (size_t)v * 192 + di * 64 + (dh & 1) * 32 + c4 * 8;
    short8 st;
    st[0] = f2bfs((float)o01[0] * inv); st[1] = f2bfs((float)o01[1] * inv);
    st[2] = f2bfs((float)o23[0] * inv); st[3] = f2bfs((float)o23[1] * inv);
    st[4] = f2bfs((float)o45[0] * inv); st[5] = f2bfs((float)o45[1] * inv);
    st[6] = f2bfs((float)o67[0] * inv); st[7] = f2bfs((float)o67[1] * inv);
    *reinterpret_cast<short8*>(op) = st;
}

// ---------------------------------------------------------------------------
extern "C" void kernel_launch(void* const* d_in, const int* in_sizes, int n_in,
                              void* d_out, int out_size, void* d_ws, size_t ws_size,
                              hipStream_t stream) {
    const float* x      = (const float*)d_in[0];
    const float* qkv_w  = (const float*)d_in[1];
    const float* proj_w = (const float*)d_in[2];
    const float* proj_b = (const float*)d_in[3];
    const float* g1     = (const float*)d_in[4];
    const float* be1    = (const float*)d_in[5];
    const float* g2     = (const float*)d_in[6];
    const float* be2    = (const float*)d_in[7];
    const float* w1     = (const float*)d_in[8];
    const float* b1     = (const float*)d_in[9];
    const float* w2     = (const float*)d_in[10];
    const float* b2     = (const float*)d_in[11];
    float* out = (float*)d_out;

    char* p = (char*)d_ws;
    bf16* h     = (bf16*)p;  p += (size_t)NV * 192 * 2;
    bf16* lnb   = (bf16*)p;  p += (size_t)NV * 192 * 2;
    bf16* qkvb  = (bf16*)p;  p += (size_t)NV * 576 * 2;
    bf16* attnb = (bf16*)p;  p += (size_t)NV * 192 * 2;
    bf16* tb    = qkvb;  // [NV][768] overlaps dead qkvb+attnb exactly
    bf16* wqkv  = (bf16*)p;  p += (size_t)576 * 192 * 2;
    bf16* wproj = (bf16*)p;  p += (size_t)192 * 192 * 2;
    bf16* w1t   = (bf16*)p;  p += (size_t)768 * 192 * 2;
    bf16* w2t   = (bf16*)p;  p += (size_t)192 * 768 * 2;

    _Float16* qa = (_Float16*)qkvb;
    _Float16* ka = qa + (size_t)6 * NV * 32;
    _Float16* va = qa + (size_t)12 * NV * 32;

    prep_kernel<<<(442368 + 255) / 256, 256, 0, stream>>>(
        qkv_w, proj_w, w1, w2, wqkv, wproj, w1t, w2t);
    tin_ln_kernel<<<1024, 256, 0, stream>>>(x, g1, be1, h, lnb);

    mgemm_kernel<3><<<dim3(NV / 128, 576 / 64), 256, 0, stream>>>(
        lnb, wqkv, qkvb, nullptr, nullptr, NV, 576, 192);
    attn_kernel<<<6144, 128, 0, stream>>>(qa, ka, va, attnb);
    projln_kernel<<<NV / 64, 256, 0, stream>>>(
        attnb, wproj, h, lnb, proj_b, g2, be2);

    mgemm_kernel<2><<<dim3(NV / 128, HIDDEN / 64), 256, 0, stream>>>(
        lnb, w1t, tb, b1, nullptr, NV, HIDDEN, 192);
    mgemm_kernel<1><<<dim3(NV / 128, 192 / 64), 256, 0, stream>>>(
        tb, w2t, h, b2, h, NV, 192, HIDDEN);

    tout_kernel<<<1024, 256, 0, stream>>>(h, out);
}